// Round 14
// baseline (484.930 us; speedup 1.0000x reference)
//
#include <hip/hip_runtime.h>

// SlotAttention fused implementation (bf16 hln, dual layout, MFMA everywhere).
//   - 6-layer linear stack folded into effective 66->128 affine (Wh, bh).
//   - k,v projections folded out of the N dimension:
//       q.k_n = (wk@q) . hln_n + q.bk ;  updates = (sum attn*hln)/den @ wv + bv
//   - hln materialized bf16 in BOTH layouts: row-major [NB][128] (k4 phase-1 A)
//     and transposed [128][NB] (k4 phase-2 B). 128 MB total, L3-resident.
//   - slot init: JAX partitionable threefry: bits[i] = o0^o1, counter (0,i).
//   - k2: MFMA GEMM with split-bf16 (hi+lo) operands => f32-level accuracy.
//     K padded 66->96. B-operand = WhiT/WloT bf16 [128][96] from k1.
//     Outputs bounced through LDS tile -> coalesced hlnb AND hlnT stores.
//   - k4: per-wave 64-row tile; MFMA phase1 + shfl softmax + MFMA phase2;
//     per-slab partial outputs (NO atomics) -> k5 reduces 128 slabs.

#define B_  8
#define N_  32768
#define NB_ (B_ * N_)   // 262144 rows
#define D_  128
#define S_  8

typedef unsigned int u32;
typedef unsigned short u16;
typedef __attribute__((ext_vector_type(8))) short bf16x8;
typedef __attribute__((ext_vector_type(4))) float f32x4;

__device__ inline u32 bfr1(float x) {  // f32 -> bf16 (RNE)
    u32 u = __float_as_uint(x);
    return (u + 0x7FFFu + ((u >> 16) & 1u)) >> 16;
}
__device__ inline u32 bfpack2(u32 lo, u32 hi) { return lo | (hi << 16); }

// pack two split values: returns hi-pair, writes lo-pair
__device__ inline u32 packsplit(float e0, float e1, u32& lopack) {
    u32 h0 = bfr1(e0), h1 = bfr1(e1);
    float r0 = e0 - __uint_as_float(h0 << 16);
    float r1 = e1 - __uint_as_float(h1 << 16);
    lopack = bfr1(r0) | (bfr1(r1) << 16);
    return h0 | (h1 << 16);
}

// threefry2x32, key = (0, 42)  (jax.random.key(42))
__device__ inline void threefry42(u32 c0, u32 c1, u32& o0, u32& o1) {
    const u32 k0 = 0u, k1 = 42u, k2 = 0x1BD11BDAu ^ 0u ^ 42u;
    const u32 ks[3] = {k0, k1, k2};
    u32 x0 = c0 + k0, x1 = c1 + k1;
    const int rA[4] = {13, 15, 26, 6}, rB[4] = {17, 29, 16, 24};
#pragma unroll
    for (int i = 0; i < 5; i++) {
#pragma unroll
        for (int k = 0; k < 4; k++) {
            int r = (i & 1) ? rB[k] : rA[k];
            x0 += x1;
            x1 = (x1 << r) | (x1 >> (32 - r));
            x1 ^= x0;
        }
        x0 += ks[(i + 1) % 3];
        x1 += ks[(i + 2) % 3] + (u32)(i + 1);
    }
    o0 = x0; o1 = x1;
}

// jax uniform(-0.99999994, 1) -> sqrt(2)*erfinv  (XLA ErfInv32 polynomial)
__device__ inline float bits_to_normal(u32 b) {
    float f = __uint_as_float((b >> 9) | 0x3f800000u) - 1.0f;  // [0,1)
    const float lo = -0.99999994f;
    float r = fmaxf(lo, f * 1.99999994f + lo);
    float w = -log1pf(-r * r);
    float p;
    if (w < 5.0f) {
        w -= 2.5f;
        p = 2.81022636e-08f;
        p = fmaf(p, w, 3.43273939e-07f);
        p = fmaf(p, w, -3.5233877e-06f);
        p = fmaf(p, w, -4.39150654e-06f);
        p = fmaf(p, w, 0.00021858087f);
        p = fmaf(p, w, -0.00125372503f);
        p = fmaf(p, w, -0.00417768164f);
        p = fmaf(p, w, 0.246640727f);
        p = fmaf(p, w, 1.50140941f);
    } else {
        w = sqrtf(w) - 3.0f;
        p = -0.000200214257f;
        p = fmaf(p, w, 0.000100950558f);
        p = fmaf(p, w, 0.00134934322f);
        p = fmaf(p, w, -0.00367342844f);
        p = fmaf(p, w, 0.00573950773f);
        p = fmaf(p, w, -0.0076224613f);
        p = fmaf(p, w, 0.00943887047f);
        p = fmaf(p, w, 1.00167406f);
        p = fmaf(p, w, 2.83297682f);
    }
    return 1.41421356f * (p * r);
}

// 128-thread block sum (2 waves), red = 2-float shared scratch
__device__ inline float block128_sum(float v, float* red) {
#pragma unroll
    for (int o = 32; o; o >>= 1) v += __shfl_down(v, o);
    __syncthreads();
    if ((threadIdx.x & 63) == 0) red[threadIdx.x >> 6] = v;
    __syncthreads();
    return red[0] + red[1];
}

// LN(slot row) -> q -> qtilde(scaled), qc(scaled).
__device__ void emit_q(float x, int bs,
                       const float* lnsg, const float* lnsb,
                       const float* wq, const float* bq,
                       const float* wkT, const float* bk,
                       float* qt, float* qc,
                       float* shA, float* red) {
    int t = threadIdx.x;
    float m = block128_sum(x, red) * (1.0f / 128.0f);
    float e = x - m;
    float var = block128_sum(e * e, red) * (1.0f / 128.0f);
    float inv = rsqrtf(var + 1e-5f);
    __syncthreads();
    shA[t] = fmaf(e * inv, lnsg[t], lnsb[t]);
    __syncthreads();
    float q = bq[t];
#pragma unroll 4
    for (int i = 0; i < 128; i++) q = fmaf(shA[i], wq[i * 128 + t], q);
    __syncthreads();
    shA[t] = q;
    __syncthreads();
    float a2 = 0.f;
#pragma unroll 4
    for (int j = 0; j < 128; j++) a2 = fmaf(wkT[j * 128 + t], shA[j], a2);
    const float scale = 0.08838834764831845f;  // 128^-0.5
    qt[bs * 128 + t] = a2 * scale;
    float pr = block128_sum(shA[t] * bk[t], red);
    if (t == 0) qc[bs] = pr * scale;
}

// ---------- K0: transpose gru weights + wk for coalesced access ----------

__global__ __launch_bounds__(256) void k0_transpose(
    const float* __restrict__ wih, const float* __restrict__ whh,
    const float* __restrict__ wk,
    float* __restrict__ wihT, float* __restrict__ whhT, float* __restrict__ wkT) {
    int idx = blockIdx.x * 256 + threadIdx.x;
    if (idx < 49152) {
        int d = idx / 384, g = idx % 384;
        wihT[idx] = wih[g * 128 + d];
    } else if (idx < 98304) {
        int o = idx - 49152;
        int d = o / 384, g = o % 384;
        whhT[o] = whh[g * 128 + d];
    } else if (idx < 114688) {
        int o = idx - 98304;
        int j = o >> 7, tcol = o & 127;
        wkT[o] = wk[tcol * 128 + j];
    }
}

// ---------- K1: fold weights, init slots, split-bf16 W for k2 ----------

__global__ __launch_bounds__(256) void k1_setup(
    const float* __restrict__ w0, const float* __restrict__ b0,
    const float* __restrict__ w1, const float* __restrict__ b1,
    const float* __restrict__ w2, const float* __restrict__ b2,
    const float* __restrict__ w3, const float* __restrict__ b3,
    const float* __restrict__ w4, const float* __restrict__ b4,
    const float* __restrict__ w5, const float* __restrict__ b5,
    const float* __restrict__ w7, const float* __restrict__ b7,
    const float* __restrict__ mu, const float* __restrict__ sg,
    float* __restrict__ Wh, float* __restrict__ bh, float* __restrict__ slots,
    u16* __restrict__ whiT, u16* __restrict__ wloT) {
    __shared__ float A[192], Bt[96], bb[64], bb2[32];
    __shared__ float stats[2];
    int t = threadIdx.x;
    for (int i = t; i < 192; i += 256) A[i] = w0[i];
    for (int i = t; i < 64; i += 256) bb[i] = b0[i];
    __syncthreads();
    const float* wl[5] = {w1, w2, w3, w4, w5};
    const float* bl[5] = {b1, b2, b3, b4, b5};
    int kin = 64;
    for (int l = 0; l < 5; l++) {
        const float* w = wl[l];
        const float* bias = bl[l];
        if (t < 96) {
            int i = t / 32, j = t % 32;
            float acc = 0.f;
            for (int k = 0; k < kin; k++) acc += A[i * kin + k] * w[k * 32 + j];
            Bt[i * 32 + j] = acc;
        } else if (t < 128) {
            int j = t - 96;
            float acc = bias[j];
            for (int k = 0; k < kin; k++) acc += bb[k] * w[k * 32 + j];
            bb2[j] = acc;
        }
        __syncthreads();
        if (t < 96) A[t] = Bt[t];
        if (t < 32) bb[t] = bb2[t];
        __syncthreads();
        kin = 32;
    }
    for (int idx = t; idx < 66 * 128; idx += 256) {
        int i = idx >> 7, j = idx & 127;
        float acc = w7[idx];
        if (i < 3) {
            for (int k = 0; k < 32; k++) acc += A[i * 32 + k] * w7[(66 + k) * 128 + j];
        }
        Wh[idx] = acc;
    }
    for (int j = t; j < 128; j += 256) {
        float acc = b7[j];
        for (int k = 0; k < 32; k++) acc += bb[k] * w7[(66 + k) * 128 + j];
        bh[j] = acc;
    }
    if (t == 0) {
        float s1 = 0.f, s2 = 0.f;
        for (int d = 0; d < 128; d++) { s1 += mu[d]; s2 += sg[d]; }
        float mmu = s1 / 128.f, msg = s2 / 128.f;
        float ss = 0.f;
        for (int d = 0; d < 128; d++) { float e = sg[d] - msg; ss += e * e; }
        stats[0] = mmu;
        stats[1] = sqrtf(64.f * ss / 8191.f);  // std over broadcast 8192, ddof=1
    }
    __syncthreads();
    // split-bf16 transposed+padded W for k2: whiT/wloT[col][k], K=96
    for (int idx = t; idx < 128 * 96; idx += 256) {
        int col = idx / 96, k = idx - col * 96;
        float v = (k < 66) ? Wh[k * 128 + col] : 0.f;
        u32 h = bfr1(v);
        float r = v - __uint_as_float(h << 16);
        whiT[idx] = (u16)h;
        wloT[idx] = (u16)bfr1(r);
    }
    float mean = stats[0], sd = stats[1];
    for (int p = t; p < 8192; p += 256) {
        u32 o0, o1;
        threefry42(0u, (u32)p, o0, o1);
        slots[p] = fmaf(sd, bits_to_normal(o0 ^ o1), mean);
    }
}

// ---------- K2: MFMA build of hln (bf16, row-major AND transposed) ----------
// 128 rows/block, 4 waves x 32 rows (2 m-tiles). Split-bf16 GEMM, K=96.
// Epilogue: LN via shfl, bf16 -> LDS tile T[128][136] -> coalesced stores.

__global__ __launch_bounds__(256) void k2_hln(
    const float* __restrict__ inputs, const float* __restrict__ embed,
    const u16* __restrict__ whiT, const u16* __restrict__ wloT,
    const float* __restrict__ bh,
    const float* __restrict__ g, const float* __restrict__ bbias,
    u16* __restrict__ hlnb, u16* __restrict__ hlnT) {
    __shared__ __align__(16) char smem[51200];   // ebuf f32[128][100] / T u16[128][136]
    __shared__ float bhl[128], gl[128], bl[128];
    int t = threadIdx.x;
    float* ebuf = (float*)smem;
    size_t rbase = (size_t)blockIdx.x * 128;
    for (int idx = t; idx < 384; idx += 256)
        ebuf[(idx / 3) * 100 + (idx % 3)] = inputs[rbase * 3 + idx];
    for (int idx = t; idx < 128 * 63; idx += 256) {
        int r = idx / 63, i = idx - r * 63;
        ebuf[r * 100 + 3 + i] = embed[rbase * 63 + idx];
    }
    for (int idx = t; idx < 128 * 34; idx += 256) {
        int r = idx / 34, i = idx - r * 34;
        ebuf[r * 100 + 66 + i] = 0.f;
    }
    if (t < 128) { bhl[t] = bh[t]; gl[t] = g[t]; bl[t] = bbias[t]; }
    __syncthreads();

    int w = t >> 6, l = t & 63;
    int c16 = l & 15, g4 = l >> 4;
    int wr0 = w * 32;
    float bhc[8], gc[8], bc[8];
#pragma unroll
    for (int nt = 0; nt < 8; nt++) {
        bhc[nt] = bhl[nt * 16 + c16];
        gc[nt] = gl[nt * 16 + c16];
        bc[nt] = bl[nt * 16 + c16];
    }
    f32x4 acc[2][8];
#pragma unroll
    for (int mi = 0; mi < 2; mi++)
#pragma unroll
        for (int nt = 0; nt < 8; nt++)
            acc[mi][nt] = (f32x4){bhc[nt], bhc[nt], bhc[nt], bhc[nt]};

#pragma unroll
    for (int kc = 0; kc < 3; kc++) {
        bf16x8 ahi[2], alo[2];
#pragma unroll
        for (int mi = 0; mi < 2; mi++) {
            const float* ep = ebuf + (wr0 + mi * 16 + c16) * 100 + kc * 32 + g4 * 8;
            float4 a = *(const float4*)ep;
            float4 b = *(const float4*)(ep + 4);
            uint4 hw, lw;
            hw.x = packsplit(a.x, a.y, lw.x);
            hw.y = packsplit(a.z, a.w, lw.y);
            hw.z = packsplit(b.x, b.y, lw.z);
            hw.w = packsplit(b.z, b.w, lw.w);
            ahi[mi] = *(bf16x8*)&hw;
            alo[mi] = *(bf16x8*)&lw;
        }
#pragma unroll
        for (int nt = 0; nt < 8; nt++) {
            size_t boff = (size_t)(nt * 16 + c16) * 96 + kc * 32 + g4 * 8;
            uint4 bhw = *(const uint4*)(whiT + boff);
            uint4 blw = *(const uint4*)(wloT + boff);
            bf16x8 bhi = *(bf16x8*)&bhw;
            bf16x8 blo = *(bf16x8*)&blw;
#pragma unroll
            for (int mi = 0; mi < 2; mi++) {
                acc[mi][nt] = __builtin_amdgcn_mfma_f32_16x16x32_bf16(ahi[mi], bhi, acc[mi][nt], 0, 0, 0);
                acc[mi][nt] = __builtin_amdgcn_mfma_f32_16x16x32_bf16(ahi[mi], blo, acc[mi][nt], 0, 0, 0);
                acc[mi][nt] = __builtin_amdgcn_mfma_f32_16x16x32_bf16(alo[mi], bhi, acc[mi][nt], 0, 0, 0);
            }
        }
    }

    __syncthreads();               // all ebuf reads done; reuse smem as T
    u16* T = (u16*)smem;           // [128][136]
#pragma unroll
    for (int mi = 0; mi < 2; mi++) {
#pragma unroll
        for (int i = 0; i < 4; i++) {
            float s = 0.f;
#pragma unroll
            for (int nt = 0; nt < 8; nt++) s += acc[mi][nt][i];
            s += __shfl_xor(s, 1); s += __shfl_xor(s, 2);
            s += __shfl_xor(s, 4); s += __shfl_xor(s, 8);
            float m = s * (1.0f / 128.0f);
            float v = 0.f;
#pragma unroll
            for (int nt = 0; nt < 8; nt++) { float d = acc[mi][nt][i] - m; v = fmaf(d, d, v); }
            v += __shfl_xor(v, 1); v += __shfl_xor(v, 2);
            v += __shfl_xor(v, 4); v += __shfl_xor(v, 8);
            float inv = rsqrtf(v * (1.0f / 128.0f) + 1e-5f);
            int row = wr0 + mi * 16 + g4 * 4 + i;
#pragma unroll
            for (int nt = 0; nt < 8; nt++) {
                float val = fmaf((acc[mi][nt][i] - m) * inv, gc[nt], bc[nt]);
                T[row * 136 + nt * 16 + c16] = (u16)bfr1(val);
            }
        }
    }
    __syncthreads();
    // hlnb: thread -> (row = t>>1, half = t&1), 128B coalesced
    {
        int r = t >> 1, hf = t & 1;
        const u16* Tr = T + r * 136 + hf * 64;
        u16* dst = hlnb + (rbase + r) * 128 + hf * 64;
#pragma unroll
        for (int j = 0; j < 8; j++) {
            uint4 v = *(const uint4*)(Tr + j * 8);
            *(uint4*)(dst + j * 8) = v;
        }
    }
    // hlnT: thread -> (d = t>>1, row-half), 128B coalesced per d
    {
        int d = t >> 1, rh = (t & 1) * 64;
        u32 buf[32];
#pragma unroll
        for (int jj = 0; jj < 32; jj++) {
            u32 a = T[(rh + 2 * jj) * 136 + d];
            u32 b = T[(rh + 2 * jj + 1) * 136 + d];
            buf[jj] = a | (b << 16);
        }
        uint4* dst = (uint4*)(hlnT + (size_t)d * NB_ + rbase + rh);
#pragma unroll
        for (int j = 0; j < 8; j++) {
            uint4 v;
            v.x = buf[j * 4]; v.y = buf[j * 4 + 1];
            v.z = buf[j * 4 + 2]; v.w = buf[j * 4 + 3];
            dst[j] = v;
        }
    }
}

// ---------- K3: initial q from slots ----------

__global__ __launch_bounds__(128) void k3_q(
    const float* __restrict__ slots,
    const float* __restrict__ lnsg, const float* __restrict__ lnsb,
    const float* __restrict__ wq, const float* __restrict__ bq,
    const float* __restrict__ wkT, const float* __restrict__ bk,
    float* __restrict__ qt, float* __restrict__ qc) {
    __shared__ float shA[128];
    __shared__ float red[2];
    int bs = blockIdx.x;
    float x = slots[bs * 128 + threadIdx.x];
    emit_q(x, bs, lnsg, lnsb, wq, bq, wkT, bk, qt, qc, shA, red);
}

// ---------- K4: MFMA attention pass, per-slab partial outputs ----------

__global__ __launch_bounds__(256) void k4_attn(
    const uint4* __restrict__ hlnb4, const u16* __restrict__ hlnT,
    const float* __restrict__ qt, const float* __restrict__ qc,
    float* __restrict__ vecp, float* __restrict__ denp) {
    __shared__ __align__(16) u16 attn_lds[4][8 * 72];  // per-wave, padded
    __shared__ __align__(16) float vlds[4][1024];
    __shared__ float dlds[4][8];
    int t = threadIdx.x;
    int w = t >> 6, l = t & 63;
    int blk = blockIdx.x;
    int b = blk >> 7, slab = blk & 127;
    size_t row0 = (size_t)b * N_ + (size_t)slab * 256 + (size_t)w * 64;
    int c16 = l & 15, g = l >> 4;

    bf16x8 qf[4];
#pragma unroll
    for (int kc = 0; kc < 4; kc++) {
        uint4 qu = {0u, 0u, 0u, 0u};
        if (c16 < 8) {
            const float* qp = qt + b * 1024 + c16 * 128 + kc * 32 + g * 8;
            float4 qa = *(const float4*)qp;
            float4 qb = *(const float4*)(qp + 4);
            qu.x = bfpack2(bfr1(qa.x), bfr1(qa.y));
            qu.y = bfpack2(bfr1(qa.z), bfr1(qa.w));
            qu.z = bfpack2(bfr1(qb.x), bfr1(qb.y));
            qu.w = bfpack2(bfr1(qb.z), bfr1(qb.w));
        }
        qf[kc] = *(bf16x8*)&qu;
    }
    float qcv = (c16 < 8) ? qc[b * 8 + c16] : 0.f;

    f32x4 dacc[4];
#pragma unroll
    for (int mt = 0; mt < 4; mt++) dacc[mt] = (f32x4){0.f, 0.f, 0.f, 0.f};
#pragma unroll
    for (int mt = 0; mt < 4; mt++) {
        uint4 au0 = hlnb4[(row0 + mt * 16 + c16) * 16 + 0 + g];
        uint4 au1 = hlnb4[(row0 + mt * 16 + c16) * 16 + 4 + g];
        uint4 au2 = hlnb4[(row0 + mt * 16 + c16) * 16 + 8 + g];
        uint4 au3 = hlnb4[(row0 + mt * 16 + c16) * 16 + 12 + g];
        dacc[mt] = __builtin_amdgcn_mfma_f32_16x16x32_bf16(*(bf16x8*)&au0, qf[0], dacc[mt], 0, 0, 0);
        dacc[mt] = __builtin_amdgcn_mfma_f32_16x16x32_bf16(*(bf16x8*)&au1, qf[1], dacc[mt], 0, 0, 0);
        dacc[mt] = __builtin_amdgcn_mfma_f32_16x16x32_bf16(*(bf16x8*)&au2, qf[2], dacc[mt], 0, 0, 0);
        dacc[mt] = __builtin_amdgcn_mfma_f32_16x16x32_bf16(*(bf16x8*)&au3, qf[3], dacc[mt], 0, 0, 0);
    }

    float denacc = 0.f;
#pragma unroll
    for (int mt = 0; mt < 4; mt++) {
        float pv[4];
#pragma unroll
        for (int r = 0; r < 4; r++) {
            float v = dacc[mt][r] + qcv;
            float mx = v;
            mx = fmaxf(mx, __shfl_xor(mx, 1));
            mx = fmaxf(mx, __shfl_xor(mx, 2));
            mx = fmaxf(mx, __shfl_xor(mx, 4));
            float e = __expf(v - mx);
            float ssum = e;
            ssum += __shfl_xor(ssum, 1);
            ssum += __shfl_xor(ssum, 2);
            ssum += __shfl_xor(ssum, 4);
            float a = fmaf(e, 1.0f / ssum, 1e-8f);
            pv[r] = a;
            denacc += a;
        }
        if (c16 < 8) {
            uint2 pw;
            pw.x = bfpack2(bfr1(pv[0]), bfr1(pv[1]));
            pw.y = bfpack2(bfr1(pv[2]), bfr1(pv[3]));
            *(uint2*)&attn_lds[w][c16 * 72 + mt * 16 + g * 4] = pw;
        }
    }
    denacc += __shfl_xor(denacc, 16);
    denacc += __shfl_xor(denacc, 32);
    if (l < 8) dlds[w][l] = denacc;

    f32x4 uacc[8];
#pragma unroll
    for (int nt = 0; nt < 8; nt++) uacc[nt] = (f32x4){0.f, 0.f, 0.f, 0.f};
#pragma unroll
    for (int kr = 0; kr < 2; kr++) {
        uint4 afu = *(const uint4*)&attn_lds[w][c16 * 72 + kr * 32 + g * 8];
        bf16x8 af = *(bf16x8*)&afu;
#pragma unroll
        for (int nt = 0; nt < 8; nt++) {
            const u16* bp = hlnT + (size_t)(nt * 16 + c16) * NB_ + row0 + kr * 32 + g * 8;
            uint4 bu = *(const uint4*)bp;
            uacc[nt] = __builtin_amdgcn_mfma_f32_16x16x32_bf16(af, *(bf16x8*)&bu, uacc[nt], 0, 0, 0);
        }
    }
    if (g < 2) {
#pragma unroll
        for (int nt = 0; nt < 8; nt++) {
#pragma unroll
            for (int r = 0; r < 4; r++) {
                vlds[w][(g * 4 + r) * 128 + nt * 16 + c16] = uacc[nt][r];
            }
        }
    }
    __syncthreads();
    float* vout = vecp + ((size_t)(b * 128 + slab) << 10);
#pragma unroll
    for (int rep = 0; rep < 4; rep++) {
        int o = rep * 256 + t;
        vout[o] = vlds[0][o] + vlds[1][o] + vlds[2][o] + vlds[3][o];
    }
    if (t < 8) denp[(b * 128 + slab) * 8 + t] = dlds[0][t] + dlds[1][t] + dlds[2][t] + dlds[3][t];
}

// ---------- K5: reduce slabs -> updates -> GRU -> MLP -> slots (+ next q) ----------

__global__ __launch_bounds__(128) void k5_update(
    const float* __restrict__ vecp, const float* __restrict__ denp,
    const float* __restrict__ wv, const float* __restrict__ bv,
    const float* __restrict__ wihT, const float* __restrict__ whhT,
    const float* __restrict__ bih, const float* __restrict__ bhh,
    const float* __restrict__ lnfg, const float* __restrict__ lnfb,
    const float* __restrict__ m1w, const float* __restrict__ m1b,
    const float* __restrict__ m2w, const float* __restrict__ m2b,
    float* __restrict__ slots,
    const float* __restrict__ lnsg, const float* __restrict__ lnsb,
    const float* __restrict__ wq, const float* __restrict__ bq,
    const float* __restrict__ wkT, const float* __restrict__ bk,
    float* __restrict__ qt, float* __restrict__ qc,
    float* __restrict__ out, int compute_q, int write_out) {
    __shared__ float sA[128], sB[128], sC[128];
    __shared__ float red[2];
    int bs = blockIdx.x, t = threadIdx.x;
    int b = bs >> 3, slot = bs & 7;
    float vsum = 0.f;
    const float* vp0 = vecp + ((size_t)(b * 128) << 10) + slot * 128 + t;
#pragma unroll 8
    for (int s = 0; s < 128; s++) vsum += vp0[(size_t)s << 10];
    float dpart = denp[(b * 128 + t) * 8 + slot];
    float dv = block128_sum(dpart, red);
    sA[t] = vsum / dv;
    sC[t] = slots[bs * 128 + t];
    __syncthreads();
    float upd = bv[t];
#pragma unroll 4
    for (int i = 0; i < 128; i++) upd = fmaf(sA[i], wv[i * 128 + t], upd);
    __syncthreads();
    sB[t] = upd;
    __syncthreads();
    float gi[3], gh[3];
#pragma unroll 1
    for (int gx = 0; gx < 3; gx++) {
        int g = gx * 128 + t;
        float a = bih[g], hh = bhh[g];
#pragma unroll 4
        for (int d = 0; d < 128; d++) {
            a = fmaf(sB[d], wihT[d * 384 + g], a);
            hh = fmaf(sC[d], whhT[d * 384 + g], hh);
        }
        gi[gx] = a; gh[gx] = hh;
    }
    float rg = 1.f / (1.f + expf(-(gi[0] + gh[0])));
    float zg = 1.f / (1.f + expf(-(gi[1] + gh[1])));
    float ng = tanhf(fmaf(rg, gh[2], gi[2]));
    float hnew = (1.f - zg) * ng + zg * sC[t];
    float m = block128_sum(hnew, red) * (1.0f / 128.0f);
    float e = hnew - m;
    float var = block128_sum(e * e, red) * (1.0f / 128.0f);
    float inv = rsqrtf(var + 1e-5f);
    __syncthreads();
    sA[t] = fmaf(e * inv, lnfg[t], lnfb[t]);
    __syncthreads();
    float m1 = m1b[t];
#pragma unroll 4
    for (int i = 0; i < 128; i++) m1 = fmaf(sA[i], m1w[i * 128 + t], m1);
    __syncthreads();
    sB[t] = m1;
    __syncthreads();
    float m2 = m2b[t];
#pragma unroll 4
    for (int i = 0; i < 128; i++) m2 = fmaf(sB[i], m2w[i * 128 + t], m2);
    float snew = hnew + m2;
    slots[bs * 128 + t] = snew;
    if (write_out) out[bs * 128 + t] = snew;
    if (compute_q) {
        emit_q(snew, bs, lnsg, lnsb, wq, bq, wkT, bk, qt, qc, sA, red);
    }
}

// ---------- launch ----------

extern "C" void kernel_launch(void* const* d_in, const int* in_sizes, int n_in,
                              void* d_out, int out_size, void* d_ws, size_t ws_size,
                              hipStream_t stream) {
    const float* inputs = (const float*)d_in[0];
    const float* embed  = (const float*)d_in[1];
    const float* mu     = (const float*)d_in[2];
    const float* sg     = (const float*)d_in[3];
    const float* w0 = (const float*)d_in[4];  const float* b0 = (const float*)d_in[5];
    const float* w1 = (const float*)d_in[6];  const float* b1 = (const float*)d_in[7];
    const float* w2 = (const float*)d_in[8];  const float* b2 = (const float*)d_in[9];
    const float* w3 = (const float*)d_in[10]; const float* b3 = (const float*)d_in[11];
    const float* w4 = (const float*)d_in[12]; const float* b4 = (const float*)d_in[13];
    const float* w5 = (const float*)d_in[14]; const float* b5 = (const float*)d_in[15];
    const float* w7 = (const float*)d_in[16]; const float* b7 = (const float*)d_in[17];
    const float* wq = (const float*)d_in[18]; const float* bq = (const float*)d_in[19];
    const float* wk = (const float*)d_in[20]; const float* bk = (const float*)d_in[21];
    const float* wv = (const float*)d_in[22]; const float* bv = (const float*)d_in[23];
    const float* ln_in_g = (const float*)d_in[24]; const float* ln_in_b = (const float*)d_in[25];
    const float* ln_sl_g = (const float*)d_in[26]; const float* ln_sl_b = (const float*)d_in[27];
    const float* ln_ff_g = (const float*)d_in[28]; const float* ln_ff_b = (const float*)d_in[29];
    const float* gwih = (const float*)d_in[30]; const float* gwhh = (const float*)d_in[31];
    const float* gbih = (const float*)d_in[32]; const float* gbhh = (const float*)d_in[33];
    const float* m1w = (const float*)d_in[34]; const float* m1b = (const float*)d_in[35];
    const float* m2w = (const float*)d_in[36]; const float* m2b = (const float*)d_in[37];

    char* ws = (char*)d_ws;
    u16* hlnb = (u16*)ws;
    size_t off = (size_t)NB_ * 128 * 2;  // 64 MB bf16 hln row-major
    u16* hlnT = (u16*)(ws + off); off += (size_t)NB_ * 128 * 2;  // 64 MB transposed
    float* Wh    = (float*)(ws + off); off += 66 * 128 * 4;
    float* bh    = (float*)(ws + off); off += 128 * 4;
    float* slots = (float*)(ws + off); off += 64 * 128 * 4;
    float* qt    = (float*)(ws + off); off += 64 * 128 * 4;
    float* qc    = (float*)(ws + off); off += 64 * 4;
    float* vecp  = (float*)(ws + off); off += (size_t)1024 * 1024 * 4;  // 4 MB
    float* denp  = (float*)(ws + off); off += 1024 * 8 * 4;
    float* wihT  = (float*)(ws + off); off += 384 * 128 * 4;
    float* whhT  = (float*)(ws + off); off += 384 * 128 * 4;
    float* wkT   = (float*)(ws + off); off += 128 * 128 * 4;
    u16* whiT    = (u16*)(ws + off); off += 128 * 96 * 2;
    u16* wloT    = (u16*)(ws + off); off += 128 * 96 * 2;

    k0_transpose<<<448, 256, 0, stream>>>(gwih, gwhh, wk, wihT, whhT, wkT);
    k1_setup<<<1, 256, 0, stream>>>(w0, b0, w1, b1, w2, b2, w3, b3, w4, b4, w5, b5,
                                    w7, b7, mu, sg, Wh, bh, slots, whiT, wloT);
    k2_hln<<<NB_ / 128, 256, 0, stream>>>(inputs, embed, whiT, wloT, bh,
                                          ln_in_g, ln_in_b, hlnb, hlnT);
    k3_q<<<64, 128, 0, stream>>>(slots, ln_sl_g, ln_sl_b, wq, bq, wkT, bk, qt, qc);
    for (int it = 0; it < 3; it++) {
        k4_attn<<<1024, 256, 0, stream>>>((const uint4*)hlnb, hlnT, qt, qc, vecp, denp);
        k5_update<<<64, 128, 0, stream>>>(vecp, denp, wv, bv, wihT, whhT, gbih, gbhh,
                                          ln_ff_g, ln_ff_b, m1w, m1b, m2w, m2b, slots,
                                          ln_sl_g, ln_sl_b, wq, bq, wkT, bk, qt, qc,
                                          (float*)d_out, (it < 2) ? 1 : 0, (it == 2) ? 1 : 0);
    }
}

// Round 15
// 456.037 us; speedup vs baseline: 1.0634x; 1.0634x over previous
//
#include <hip/hip_runtime.h>

// SlotAttention fused implementation (bf16 hln, single layout, MFMA).
//   - 6-layer linear stack folded into effective 66->128 affine (Wh, bh).
//   - k,v projections folded out of the N dimension:
//       q.k_n = (wk@q) . hln_n + q.bk ;  updates = (sum attn*hln)/den @ wv + bv
//   - hln bf16 row-major [NB][128] ONLY (64 MB). k4 phase-2 re-uses the
//     phase-1 loads via a per-wave LDS tile (no transposed global copy).
//   - slot init: JAX partitionable threefry: bits[i] = o0^o1, counter (0,i).
//   - k2: split-bf16 MFMA GEMM (hi+lo), K=96, epilogue -> hlnb only.
//   - k4: 2048 blocks x 4 waves x 32 rows; MFMA phase1 + stage tile;
//     shfl softmax; phase2 B-frags from LDS columns; 2-buffer vlds reduce;
//     per-slab partials (no atomics) -> k5 reduces 256 slabs.

#define B_  8
#define N_  32768
#define NB_ (B_ * N_)   // 262144 rows
#define D_  128
#define S_  8

typedef unsigned int u32;
typedef unsigned short u16;
typedef __attribute__((ext_vector_type(8))) short bf16x8;
typedef __attribute__((ext_vector_type(4))) float f32x4;

__device__ inline u32 bfr1(float x) {  // f32 -> bf16 (RNE)
    u32 u = __float_as_uint(x);
    return (u + 0x7FFFu + ((u >> 16) & 1u)) >> 16;
}
__device__ inline u32 bfpack2(u32 lo, u32 hi) { return lo | (hi << 16); }

__device__ inline u32 packsplit(float e0, float e1, u32& lopack) {
    u32 h0 = bfr1(e0), h1 = bfr1(e1);
    float r0 = e0 - __uint_as_float(h0 << 16);
    float r1 = e1 - __uint_as_float(h1 << 16);
    lopack = bfr1(r0) | (bfr1(r1) << 16);
    return h0 | (h1 << 16);
}

// threefry2x32, key = (0, 42)
__device__ inline void threefry42(u32 c0, u32 c1, u32& o0, u32& o1) {
    const u32 k0 = 0u, k1 = 42u, k2 = 0x1BD11BDAu ^ 0u ^ 42u;
    const u32 ks[3] = {k0, k1, k2};
    u32 x0 = c0 + k0, x1 = c1 + k1;
    const int rA[4] = {13, 15, 26, 6}, rB[4] = {17, 29, 16, 24};
#pragma unroll
    for (int i = 0; i < 5; i++) {
#pragma unroll
        for (int k = 0; k < 4; k++) {
            int r = (i & 1) ? rB[k] : rA[k];
            x0 += x1;
            x1 = (x1 << r) | (x1 >> (32 - r));
            x1 ^= x0;
        }
        x0 += ks[(i + 1) % 3];
        x1 += ks[(i + 2) % 3] + (u32)(i + 1);
    }
    o0 = x0; o1 = x1;
}

// jax uniform(-0.99999994, 1) -> sqrt(2)*erfinv
__device__ inline float bits_to_normal(u32 b) {
    float f = __uint_as_float((b >> 9) | 0x3f800000u) - 1.0f;
    const float lo = -0.99999994f;
    float r = fmaxf(lo, f * 1.99999994f + lo);
    float w = -log1pf(-r * r);
    float p;
    if (w < 5.0f) {
        w -= 2.5f;
        p = 2.81022636e-08f;
        p = fmaf(p, w, 3.43273939e-07f);
        p = fmaf(p, w, -3.5233877e-06f);
        p = fmaf(p, w, -4.39150654e-06f);
        p = fmaf(p, w, 0.00021858087f);
        p = fmaf(p, w, -0.00125372503f);
        p = fmaf(p, w, -0.00417768164f);
        p = fmaf(p, w, 0.246640727f);
        p = fmaf(p, w, 1.50140941f);
    } else {
        w = sqrtf(w) - 3.0f;
        p = -0.000200214257f;
        p = fmaf(p, w, 0.000100950558f);
        p = fmaf(p, w, 0.00134934322f);
        p = fmaf(p, w, -0.00367342844f);
        p = fmaf(p, w, 0.00573950773f);
        p = fmaf(p, w, -0.0076224613f);
        p = fmaf(p, w, 0.00943887047f);
        p = fmaf(p, w, 1.00167406f);
        p = fmaf(p, w, 2.83297682f);
    }
    return 1.41421356f * (p * r);
}

__device__ inline float block128_sum(float v, float* red) {
#pragma unroll
    for (int o = 32; o; o >>= 1) v += __shfl_down(v, o);
    __syncthreads();
    if ((threadIdx.x & 63) == 0) red[threadIdx.x >> 6] = v;
    __syncthreads();
    return red[0] + red[1];
}

__device__ void emit_q(float x, int bs,
                       const float* lnsg, const float* lnsb,
                       const float* wq, const float* bq,
                       const float* wkT, const float* bk,
                       float* qt, float* qc,
                       float* shA, float* red) {
    int t = threadIdx.x;
    float m = block128_sum(x, red) * (1.0f / 128.0f);
    float e = x - m;
    float var = block128_sum(e * e, red) * (1.0f / 128.0f);
    float inv = rsqrtf(var + 1e-5f);
    __syncthreads();
    shA[t] = fmaf(e * inv, lnsg[t], lnsb[t]);
    __syncthreads();
    float q = bq[t];
#pragma unroll 4
    for (int i = 0; i < 128; i++) q = fmaf(shA[i], wq[i * 128 + t], q);
    __syncthreads();
    shA[t] = q;
    __syncthreads();
    float a2 = 0.f;
#pragma unroll 4
    for (int j = 0; j < 128; j++) a2 = fmaf(wkT[j * 128 + t], shA[j], a2);
    const float scale = 0.08838834764831845f;  // 128^-0.5
    qt[bs * 128 + t] = a2 * scale;
    float pr = block128_sum(shA[t] * bk[t], red);
    if (t == 0) qc[bs] = pr * scale;
}

// ---------- K0: transpose gru weights + wk ----------

__global__ __launch_bounds__(256) void k0_transpose(
    const float* __restrict__ wih, const float* __restrict__ whh,
    const float* __restrict__ wk,
    float* __restrict__ wihT, float* __restrict__ whhT, float* __restrict__ wkT) {
    int idx = blockIdx.x * 256 + threadIdx.x;
    if (idx < 49152) {
        int d = idx / 384, g = idx % 384;
        wihT[idx] = wih[g * 128 + d];
    } else if (idx < 98304) {
        int o = idx - 49152;
        int d = o / 384, g = o % 384;
        whhT[o] = whh[g * 128 + d];
    } else if (idx < 114688) {
        int o = idx - 98304;
        int j = o >> 7, tcol = o & 127;
        wkT[o] = wk[tcol * 128 + j];
    }
}

// ---------- K1: fold weights, init slots, split-bf16 W ----------

__global__ __launch_bounds__(256) void k1_setup(
    const float* __restrict__ w0, const float* __restrict__ b0,
    const float* __restrict__ w1, const float* __restrict__ b1,
    const float* __restrict__ w2, const float* __restrict__ b2,
    const float* __restrict__ w3, const float* __restrict__ b3,
    const float* __restrict__ w4, const float* __restrict__ b4,
    const float* __restrict__ w5, const float* __restrict__ b5,
    const float* __restrict__ w7, const float* __restrict__ b7,
    const float* __restrict__ mu, const float* __restrict__ sg,
    float* __restrict__ Wh, float* __restrict__ bh, float* __restrict__ slots,
    u16* __restrict__ whiT, u16* __restrict__ wloT) {
    __shared__ float A[192], Bt[96], bb[64], bb2[32];
    __shared__ float stats[2];
    int t = threadIdx.x;
    for (int i = t; i < 192; i += 256) A[i] = w0[i];
    for (int i = t; i < 64; i += 256) bb[i] = b0[i];
    __syncthreads();
    const float* wl[5] = {w1, w2, w3, w4, w5};
    const float* bl[5] = {b1, b2, b3, b4, b5};
    int kin = 64;
    for (int l = 0; l < 5; l++) {
        const float* w = wl[l];
        const float* bias = bl[l];
        if (t < 96) {
            int i = t / 32, j = t % 32;
            float acc = 0.f;
            for (int k = 0; k < kin; k++) acc += A[i * kin + k] * w[k * 32 + j];
            Bt[i * 32 + j] = acc;
        } else if (t < 128) {
            int j = t - 96;
            float acc = bias[j];
            for (int k = 0; k < kin; k++) acc += bb[k] * w[k * 32 + j];
            bb2[j] = acc;
        }
        __syncthreads();
        if (t < 96) A[t] = Bt[t];
        if (t < 32) bb[t] = bb2[t];
        __syncthreads();
        kin = 32;
    }
    for (int idx = t; idx < 66 * 128; idx += 256) {
        int i = idx >> 7, j = idx & 127;
        float acc = w7[idx];
        if (i < 3) {
            for (int k = 0; k < 32; k++) acc += A[i * 32 + k] * w7[(66 + k) * 128 + j];
        }
        Wh[idx] = acc;
    }
    for (int j = t; j < 128; j += 256) {
        float acc = b7[j];
        for (int k = 0; k < 32; k++) acc += bb[k] * w7[(66 + k) * 128 + j];
        bh[j] = acc;
    }
    if (t == 0) {
        float s1 = 0.f, s2 = 0.f;
        for (int d = 0; d < 128; d++) { s1 += mu[d]; s2 += sg[d]; }
        float mmu = s1 / 128.f, msg = s2 / 128.f;
        float ss = 0.f;
        for (int d = 0; d < 128; d++) { float e = sg[d] - msg; ss += e * e; }
        stats[0] = mmu;
        stats[1] = sqrtf(64.f * ss / 8191.f);
    }
    __syncthreads();
    for (int idx = t; idx < 128 * 96; idx += 256) {
        int col = idx / 96, k = idx - col * 96;
        float v = (k < 66) ? Wh[k * 128 + col] : 0.f;
        u32 h = bfr1(v);
        float r = v - __uint_as_float(h << 16);
        whiT[idx] = (u16)h;
        wloT[idx] = (u16)bfr1(r);
    }
    float mean = stats[0], sd = stats[1];
    for (int p = t; p < 8192; p += 256) {
        u32 o0, o1;
        threefry42(0u, (u32)p, o0, o1);
        slots[p] = fmaf(sd, bits_to_normal(o0 ^ o1), mean);
    }
}

// ---------- K2: MFMA build of hln (bf16 row-major only) ----------

__global__ __launch_bounds__(256) void k2_hln(
    const float* __restrict__ inputs, const float* __restrict__ embed,
    const u16* __restrict__ whiT, const u16* __restrict__ wloT,
    const float* __restrict__ bh,
    const float* __restrict__ g, const float* __restrict__ bbias,
    u16* __restrict__ hlnb) {
    __shared__ __align__(16) char smem[51200];   // ebuf f32[128][100] / T u16[128][136]
    __shared__ float bhl[128], gl[128], bl[128];
    int t = threadIdx.x;
    float* ebuf = (float*)smem;
    size_t rbase = (size_t)blockIdx.x * 128;
    for (int idx = t; idx < 384; idx += 256)
        ebuf[(idx / 3) * 100 + (idx % 3)] = inputs[rbase * 3 + idx];
    for (int idx = t; idx < 128 * 63; idx += 256) {
        int r = idx / 63, i = idx - r * 63;
        ebuf[r * 100 + 3 + i] = embed[rbase * 63 + idx];
    }
    for (int idx = t; idx < 128 * 34; idx += 256) {
        int r = idx / 34, i = idx - r * 34;
        ebuf[r * 100 + 66 + i] = 0.f;
    }
    if (t < 128) { bhl[t] = bh[t]; gl[t] = g[t]; bl[t] = bbias[t]; }
    __syncthreads();

    int w = t >> 6, l = t & 63;
    int c16 = l & 15, g4 = l >> 4;
    int wr0 = w * 32;
    float bhc[8], gc[8], bc[8];
#pragma unroll
    for (int nt = 0; nt < 8; nt++) {
        bhc[nt] = bhl[nt * 16 + c16];
        gc[nt] = gl[nt * 16 + c16];
        bc[nt] = bl[nt * 16 + c16];
    }
    f32x4 acc[2][8];
#pragma unroll
    for (int mi = 0; mi < 2; mi++)
#pragma unroll
        for (int nt = 0; nt < 8; nt++)
            acc[mi][nt] = (f32x4){bhc[nt], bhc[nt], bhc[nt], bhc[nt]};

#pragma unroll
    for (int kc = 0; kc < 3; kc++) {
        bf16x8 ahi[2], alo[2];
#pragma unroll
        for (int mi = 0; mi < 2; mi++) {
            const float* ep = ebuf + (wr0 + mi * 16 + c16) * 100 + kc * 32 + g4 * 8;
            float4 a = *(const float4*)ep;
            float4 b = *(const float4*)(ep + 4);
            uint4 hw, lw;
            hw.x = packsplit(a.x, a.y, lw.x);
            hw.y = packsplit(a.z, a.w, lw.y);
            hw.z = packsplit(b.x, b.y, lw.z);
            hw.w = packsplit(b.z, b.w, lw.w);
            ahi[mi] = *(bf16x8*)&hw;
            alo[mi] = *(bf16x8*)&lw;
        }
#pragma unroll
        for (int nt = 0; nt < 8; nt++) {
            size_t boff = (size_t)(nt * 16 + c16) * 96 + kc * 32 + g4 * 8;
            uint4 bhw = *(const uint4*)(whiT + boff);
            uint4 blw = *(const uint4*)(wloT + boff);
            bf16x8 bhi = *(bf16x8*)&bhw;
            bf16x8 blo = *(bf16x8*)&blw;
#pragma unroll
            for (int mi = 0; mi < 2; mi++) {
                acc[mi][nt] = __builtin_amdgcn_mfma_f32_16x16x32_bf16(ahi[mi], bhi, acc[mi][nt], 0, 0, 0);
                acc[mi][nt] = __builtin_amdgcn_mfma_f32_16x16x32_bf16(ahi[mi], blo, acc[mi][nt], 0, 0, 0);
                acc[mi][nt] = __builtin_amdgcn_mfma_f32_16x16x32_bf16(alo[mi], bhi, acc[mi][nt], 0, 0, 0);
            }
        }
    }

    __syncthreads();
    u16* T = (u16*)smem;           // [128][136]
#pragma unroll
    for (int mi = 0; mi < 2; mi++) {
#pragma unroll
        for (int i = 0; i < 4; i++) {
            float s = 0.f;
#pragma unroll
            for (int nt = 0; nt < 8; nt++) s += acc[mi][nt][i];
            s += __shfl_xor(s, 1); s += __shfl_xor(s, 2);
            s += __shfl_xor(s, 4); s += __shfl_xor(s, 8);
            float m = s * (1.0f / 128.0f);
            float v = 0.f;
#pragma unroll
            for (int nt = 0; nt < 8; nt++) { float d = acc[mi][nt][i] - m; v = fmaf(d, d, v); }
            v += __shfl_xor(v, 1); v += __shfl_xor(v, 2);
            v += __shfl_xor(v, 4); v += __shfl_xor(v, 8);
            float inv = rsqrtf(v * (1.0f / 128.0f) + 1e-5f);
            int row = wr0 + mi * 16 + g4 * 4 + i;
#pragma unroll
            for (int nt = 0; nt < 8; nt++) {
                float val = fmaf((acc[mi][nt][i] - m) * inv, gc[nt], bc[nt]);
                T[row * 136 + nt * 16 + c16] = (u16)bfr1(val);
            }
        }
    }
    __syncthreads();
    {
        int r = t >> 1, hf = t & 1;
        const u16* Tr = T + r * 136 + hf * 64;
        u16* dst = hlnb + (rbase + r) * 128 + hf * 64;
#pragma unroll
        for (int j = 0; j < 8; j++) {
            uint4 v = *(const uint4*)(Tr + j * 8);
            *(uint4*)(dst + j * 8) = v;
        }
    }
}

// ---------- K3: initial q from slots ----------

__global__ __launch_bounds__(128) void k3_q(
    const float* __restrict__ slots,
    const float* __restrict__ lnsg, const float* __restrict__ lnsb,
    const float* __restrict__ wq, const float* __restrict__ bq,
    const float* __restrict__ wkT, const float* __restrict__ bk,
    float* __restrict__ qt, float* __restrict__ qc) {
    __shared__ float shA[128];
    __shared__ float red[2];
    int bs = blockIdx.x;
    float x = slots[bs * 128 + threadIdx.x];
    emit_q(x, bs, lnsg, lnsb, wq, bq, wkT, bk, qt, qc, shA, red);
}

// ---------- K4: MFMA attention, single-layout, LDS tile re-use ----------
// 2048 blocks x 4 waves x 32 rows. Phase1 stages tile; phase2 reads columns.

__global__ __launch_bounds__(256) void k4_attn(
    const uint4* __restrict__ hlnb4,
    const float* __restrict__ qt, const float* __restrict__ qc,
    float* __restrict__ vecp, float* __restrict__ denp) {
    __shared__ __align__(16) u16 tiles[4][32 * 132];   // 33792 B
    __shared__ __align__(16) u16 attnP[4][16 * 40];    // 5120 B
    __shared__ __align__(16) float vlds[2][1024];      // 8192 B
    __shared__ float dlds[4][8];
    int t = threadIdx.x;
    int w = t >> 6, l = t & 63;
    int blk = blockIdx.x;
    int b = blk >> 8, slab = blk & 255;
    size_t row0 = (size_t)b * N_ + (size_t)slab * 128 + (size_t)w * 32;
    int c16 = l & 15, g = l >> 4;
    u16* tw = tiles[w];

    // q B-frags (slot = c16, zero-pad c16>=8)
    bf16x8 qf[4];
#pragma unroll
    for (int kc = 0; kc < 4; kc++) {
        uint4 qu = {0u, 0u, 0u, 0u};
        if (c16 < 8) {
            const float* qp = qt + b * 1024 + c16 * 128 + kc * 32 + g * 8;
            float4 qa = *(const float4*)qp;
            float4 qb = *(const float4*)(qp + 4);
            qu.x = bfpack2(bfr1(qa.x), bfr1(qa.y));
            qu.y = bfpack2(bfr1(qa.z), bfr1(qa.w));
            qu.z = bfpack2(bfr1(qb.x), bfr1(qb.y));
            qu.w = bfpack2(bfr1(qb.z), bfr1(qb.w));
        }
        qf[kc] = *(bf16x8*)&qu;
    }
    float qcv = (c16 < 8) ? qc[b * 8 + c16] : 0.f;

    // ---- phase 1 (8 MFMA) + stage tile ----
    f32x4 dacc[2];
    dacc[0] = (f32x4){0.f, 0.f, 0.f, 0.f};
    dacc[1] = (f32x4){0.f, 0.f, 0.f, 0.f};
#pragma unroll
    for (int mt = 0; mt < 2; mt++) {
#pragma unroll
        for (int kc = 0; kc < 4; kc++) {
            uint4 au = hlnb4[(row0 + mt * 16 + c16) * 16 + kc * 4 + g];
            dacc[mt] = __builtin_amdgcn_mfma_f32_16x16x32_bf16(*(bf16x8*)&au, qf[kc], dacc[mt], 0, 0, 0);
            int off = (mt * 16 + c16) * 132 + kc * 32 + g * 8;
            uint2 lo; lo.x = au.x; lo.y = au.y;
            uint2 hi; hi.x = au.z; hi.y = au.w;
            *(uint2*)&tw[off] = lo;
            *(uint2*)&tw[off + 4] = hi;
        }
    }

    // ---- softmax over slots (c16 lanes, masks 1/2/4) ----
    float denacc = 0.f;
#pragma unroll
    for (int mt = 0; mt < 2; mt++) {
        float pv[4];
#pragma unroll
        for (int r = 0; r < 4; r++) {
            float v = dacc[mt][r] + qcv;
            float mx = v;
            mx = fmaxf(mx, __shfl_xor(mx, 1));
            mx = fmaxf(mx, __shfl_xor(mx, 2));
            mx = fmaxf(mx, __shfl_xor(mx, 4));
            float e = __expf(v - mx);
            float ssum = e;
            ssum += __shfl_xor(ssum, 1);
            ssum += __shfl_xor(ssum, 2);
            ssum += __shfl_xor(ssum, 4);
            float a = (c16 < 8) ? fmaf(e, 1.0f / ssum, 1e-8f) : 0.f;
            pv[r] = a;
            denacc += a;
        }
        uint2 pw;
        pw.x = bfpack2(bfr1(pv[0]), bfr1(pv[1]));
        pw.y = bfpack2(bfr1(pv[2]), bfr1(pv[3]));
        *(uint2*)&attnP[w][c16 * 40 + mt * 16 + g * 4] = pw;
    }
    denacc += __shfl_xor(denacc, 16);
    denacc += __shfl_xor(denacc, 32);
    if (l < 8) dlds[w][l] = denacc;

    // ---- phase 2: U[16x128] = P^T[16x32] . H[32x128] (8 MFMA) ----
    uint4 afu = *(const uint4*)&attnP[w][c16 * 40 + g * 8];
    bf16x8 af = *(bf16x8*)&afu;
    f32x4 uacc[8];
#pragma unroll
    for (int nt = 0; nt < 8; nt++) uacc[nt] = (f32x4){0.f, 0.f, 0.f, 0.f};
#pragma unroll
    for (int nt = 0; nt < 8; nt++) {
        const u16* tp = tw + nt * 16 + c16;
        u32 w0 = (u32)tp[(g * 8 + 0) * 132] | ((u32)tp[(g * 8 + 1) * 132] << 16);
        u32 w1 = (u32)tp[(g * 8 + 2) * 132] | ((u32)tp[(g * 8 + 3) * 132] << 16);
        u32 w2 = (u32)tp[(g * 8 + 4) * 132] | ((u32)tp[(g * 8 + 5) * 132] << 16);
        u32 w3 = (u32)tp[(g * 8 + 6) * 132] | ((u32)tp[(g * 8 + 7) * 132] << 16);
        uint4 bu; bu.x = w0; bu.y = w1; bu.z = w2; bu.w = w3;
        uacc[nt] = __builtin_amdgcn_mfma_f32_16x16x32_bf16(af, *(bf16x8*)&bu, uacc[nt], 0, 0, 0);
    }
    // ---- 2-buffer cross-wave reduce ----
    if (w < 2 && g < 2) {
#pragma unroll
        for (int nt = 0; nt < 8; nt++)
#pragma unroll
            for (int r = 0; r < 4; r++)
                vlds[w][(g * 4 + r) * 128 + nt * 16 + c16] = uacc[nt][r];
    }
    __syncthreads();
    if (w >= 2 && g < 2) {
#pragma unroll
        for (int nt = 0; nt < 8; nt++)
#pragma unroll
            for (int r = 0; r < 4; r++)
                vlds[w - 2][(g * 4 + r) * 128 + nt * 16 + c16] += uacc[nt][r];
    }
    __syncthreads();
    float* vout = vecp + ((size_t)blk << 10);
#pragma unroll
    for (int rep = 0; rep < 4; rep++) {
        int o = rep * 256 + t;
        vout[o] = vlds[0][o] + vlds[1][o];
    }
    if (t < 8) denp[blk * 8 + t] = dlds[0][t] + dlds[1][t] + dlds[2][t] + dlds[3][t];
}

// ---------- K5: reduce 256 slabs -> updates -> GRU -> MLP -> slots ----------

__global__ __launch_bounds__(128) void k5_update(
    const float* __restrict__ vecp, const float* __restrict__ denp,
    const float* __restrict__ wv, const float* __restrict__ bv,
    const float* __restrict__ wihT, const float* __restrict__ whhT,
    const float* __restrict__ bih, const float* __restrict__ bhh,
    const float* __restrict__ lnfg, const float* __restrict__ lnfb,
    const float* __restrict__ m1w, const float* __restrict__ m1b,
    const float* __restrict__ m2w, const float* __restrict__ m2b,
    float* __restrict__ slots,
    const float* __restrict__ lnsg, const float* __restrict__ lnsb,
    const float* __restrict__ wq, const float* __restrict__ bq,
    const float* __restrict__ wkT, const float* __restrict__ bk,
    float* __restrict__ qt, float* __restrict__ qc,
    float* __restrict__ out, int compute_q, int write_out) {
    __shared__ float sA[128], sB[128], sC[128];
    __shared__ float red[2];
    int bs = blockIdx.x, t = threadIdx.x;
    int b = bs >> 3, slot = bs & 7;
    float vsum = 0.f;
    const float* vp0 = vecp + ((size_t)(b * 256) << 10) + slot * 128 + t;
#pragma unroll 8
    for (int s = 0; s < 256; s++) vsum += vp0[(size_t)s << 10];
    float dpart = denp[(b * 256 + t) * 8 + slot] + denp[(b * 256 + 128 + t) * 8 + slot];
    float dv = block128_sum(dpart, red);
    sA[t] = vsum / dv;
    sC[t] = slots[bs * 128 + t];
    __syncthreads();
    float upd = bv[t];
#pragma unroll 4
    for (int i = 0; i < 128; i++) upd = fmaf(sA[i], wv[i * 128 + t], upd);
    __syncthreads();
    sB[t] = upd;
    __syncthreads();
    float gi[3], gh[3];
#pragma unroll 1
    for (int gx = 0; gx < 3; gx++) {
        int g = gx * 128 + t;
        float a = bih[g], hh = bhh[g];
#pragma unroll 4
        for (int d = 0; d < 128; d++) {
            a = fmaf(sB[d], wihT[d * 384 + g], a);
            hh = fmaf(sC[d], whhT[d * 384 + g], hh);
        }
        gi[gx] = a; gh[gx] = hh;
    }
    float rg = 1.f / (1.f + expf(-(gi[0] + gh[0])));
    float zg = 1.f / (1.f + expf(-(gi[1] + gh[1])));
    float ng = tanhf(fmaf(rg, gh[2], gi[2]));
    float hnew = (1.f - zg) * ng + zg * sC[t];
    float m = block128_sum(hnew, red) * (1.0f / 128.0f);
    float e = hnew - m;
    float var = block128_sum(e * e, red) * (1.0f / 128.0f);
    float inv = rsqrtf(var + 1e-5f);
    __syncthreads();
    sA[t] = fmaf(e * inv, lnfg[t], lnfb[t]);
    __syncthreads();
    float m1 = m1b[t];
#pragma unroll 4
    for (int i = 0; i < 128; i++) m1 = fmaf(sA[i], m1w[i * 128 + t], m1);
    __syncthreads();
    sB[t] = m1;
    __syncthreads();
    float m2 = m2b[t];
#pragma unroll 4
    for (int i = 0; i < 128; i++) m2 = fmaf(sB[i], m2w[i * 128 + t], m2);
    float snew = hnew + m2;
    slots[bs * 128 + t] = snew;
    if (write_out) out[bs * 128 + t] = snew;
    if (compute_q) {
        emit_q(snew, bs, lnsg, lnsb, wq, bq, wkT, bk, qt, qc, sA, red);
    }
}

// ---------- launch ----------

extern "C" void kernel_launch(void* const* d_in, const int* in_sizes, int n_in,
                              void* d_out, int out_size, void* d_ws, size_t ws_size,
                              hipStream_t stream) {
    const float* inputs = (const float*)d_in[0];
    const float* embed  = (const float*)d_in[1];
    const float* mu     = (const float*)d_in[2];
    const float* sg     = (const float*)d_in[3];
    const float* w0 = (const float*)d_in[4];  const float* b0 = (const float*)d_in[5];
    const float* w1 = (const float*)d_in[6];  const float* b1 = (const float*)d_in[7];
    const float* w2 = (const float*)d_in[8];  const float* b2 = (const float*)d_in[9];
    const float* w3 = (const float*)d_in[10]; const float* b3 = (const float*)d_in[11];
    const float* w4 = (const float*)d_in[12]; const float* b4 = (const float*)d_in[13];
    const float* w5 = (const float*)d_in[14]; const float* b5 = (const float*)d_in[15];
    const float* w7 = (const float*)d_in[16]; const float* b7 = (const float*)d_in[17];
    const float* wq = (const float*)d_in[18]; const float* bq = (const float*)d_in[19];
    const float* wk = (const float*)d_in[20]; const float* bk = (const float*)d_in[21];
    const float* wv = (const float*)d_in[22]; const float* bv = (const float*)d_in[23];
    const float* ln_in_g = (const float*)d_in[24]; const float* ln_in_b = (const float*)d_in[25];
    const float* ln_sl_g = (const float*)d_in[26]; const float* ln_sl_b = (const float*)d_in[27];
    const float* ln_ff_g = (const float*)d_in[28]; const float* ln_ff_b = (const float*)d_in[29];
    const float* gwih = (const float*)d_in[30]; const float* gwhh = (const float*)d_in[31];
    const float* gbih = (const float*)d_in[32]; const float* gbhh = (const float*)d_in[33];
    const float* m1w = (const float*)d_in[34]; const float* m1b = (const float*)d_in[35];
    const float* m2w = (const float*)d_in[36]; const float* m2b = (const float*)d_in[37];

    char* ws = (char*)d_ws;
    u16* hlnb = (u16*)ws;
    size_t off = (size_t)NB_ * 128 * 2;  // 64 MB bf16 hln row-major
    float* Wh    = (float*)(ws + off); off += 66 * 128 * 4;
    float* bh    = (float*)(ws + off); off += 128 * 4;
    float* slots = (float*)(ws + off); off += 64 * 128 * 4;
    float* qt    = (float*)(ws + off); off += 64 * 128 * 4;
    float* qc    = (float*)(ws + off); off += 64 * 4;
    float* vecp  = (float*)(ws + off); off += (size_t)2048 * 1024 * 4;  // 8 MB
    float* denp  = (float*)(ws + off); off += 2048 * 8 * 4;
    float* wihT  = (float*)(ws + off); off += 384 * 128 * 4;
    float* whhT  = (float*)(ws + off); off += 384 * 128 * 4;
    float* wkT   = (float*)(ws + off); off += 128 * 128 * 4;
    u16* whiT    = (u16*)(ws + off); off += 128 * 96 * 2;
    u16* wloT    = (u16*)(ws + off); off += 128 * 96 * 2;

    k0_transpose<<<448, 256, 0, stream>>>(gwih, gwhh, wk, wihT, whhT, wkT);
    k1_setup<<<1, 256, 0, stream>>>(w0, b0, w1, b1, w2, b2, w3, b3, w4, b4, w5, b5,
                                    w7, b7, mu, sg, Wh, bh, slots, whiT, wloT);
    k2_hln<<<NB_ / 128, 256, 0, stream>>>(inputs, embed, whiT, wloT, bh,
                                          ln_in_g, ln_in_b, hlnb);
    k3_q<<<64, 128, 0, stream>>>(slots, ln_sl_g, ln_sl_b, wq, bq, wkT, bk, qt, qc);
    for (int it = 0; it < 3; it++) {
        k4_attn<<<2048, 256, 0, stream>>>((const uint4*)hlnb, qt, qc, vecp, denp);
        k5_update<<<64, 128, 0, stream>>>(vecp, denp, wv, bv, wihT, whhT, gbih, gbhh,
                                          ln_ff_g, ln_ff_b, m1w, m1b, m2w, m2b, slots,
                                          ln_sl_g, ln_sl_b, wq, bq, wkT, bk, qt, qc,
                                          (float*)d_out, (it < 2) ? 1 : 0, (it == 2) ? 1 : 0);
    }
}

// Round 16
// 279.784 us; speedup vs baseline: 1.7332x; 1.6300x over previous
//
#include <hip/hip_runtime.h>

// SlotAttention fused implementation (bf16 hln, single layout, MFMA).
//   - 6-layer linear stack folded into effective 66->128 affine (Wh, bh).
//   - k,v folded out of N:  q.k_n = (wk@q).hln_n + q.bk ;
//     updates = (sum attn*hln)/den @ wv + bv
//   - hln bf16 row-major [NB][128] only (64 MB). k4 phase-2 re-uses phase-1
//     loads via a per-wave LDS tile.
//   - slot init: JAX partitionable threefry: bits[i] = o0^o1, counter (0,i).
//   - k2: split-bf16 MFMA GEMM (hi+lo), K=96.
//   - k4: 2048 blocks x 4 waves x 32 rows; per-slab partials (no atomics).
//   - k5: 512 threads (d x quarter); all GEMVs = 32-iter partials + LDS
//     tree reduce; 8 waves/CU hide L2 latency (was 1 wave, 98 us).

#define B_  8
#define N_  32768
#define NB_ (B_ * N_)   // 262144 rows
#define D_  128
#define S_  8

typedef unsigned int u32;
typedef unsigned short u16;
typedef __attribute__((ext_vector_type(8))) short bf16x8;
typedef __attribute__((ext_vector_type(4))) float f32x4;

__device__ inline u32 bfr1(float x) {  // f32 -> bf16 (RNE)
    u32 u = __float_as_uint(x);
    return (u + 0x7FFFu + ((u >> 16) & 1u)) >> 16;
}
__device__ inline u32 bfpack2(u32 lo, u32 hi) { return lo | (hi << 16); }

__device__ inline u32 packsplit(float e0, float e1, u32& lopack) {
    u32 h0 = bfr1(e0), h1 = bfr1(e1);
    float r0 = e0 - __uint_as_float(h0 << 16);
    float r1 = e1 - __uint_as_float(h1 << 16);
    lopack = bfr1(r0) | (bfr1(r1) << 16);
    return h0 | (h1 << 16);
}

// threefry2x32, key = (0, 42)
__device__ inline void threefry42(u32 c0, u32 c1, u32& o0, u32& o1) {
    const u32 k0 = 0u, k1 = 42u, k2 = 0x1BD11BDAu ^ 0u ^ 42u;
    const u32 ks[3] = {k0, k1, k2};
    u32 x0 = c0 + k0, x1 = c1 + k1;
    const int rA[4] = {13, 15, 26, 6}, rB[4] = {17, 29, 16, 24};
#pragma unroll
    for (int i = 0; i < 5; i++) {
#pragma unroll
        for (int k = 0; k < 4; k++) {
            int r = (i & 1) ? rB[k] : rA[k];
            x0 += x1;
            x1 = (x1 << r) | (x1 >> (32 - r));
            x1 ^= x0;
        }
        x0 += ks[(i + 1) % 3];
        x1 += ks[(i + 2) % 3] + (u32)(i + 1);
    }
    o0 = x0; o1 = x1;
}

// jax uniform(-0.99999994, 1) -> sqrt(2)*erfinv
__device__ inline float bits_to_normal(u32 b) {
    float f = __uint_as_float((b >> 9) | 0x3f800000u) - 1.0f;
    const float lo = -0.99999994f;
    float r = fmaxf(lo, f * 1.99999994f + lo);
    float w = -log1pf(-r * r);
    float p;
    if (w < 5.0f) {
        w -= 2.5f;
        p = 2.81022636e-08f;
        p = fmaf(p, w, 3.43273939e-07f);
        p = fmaf(p, w, -3.5233877e-06f);
        p = fmaf(p, w, -4.39150654e-06f);
        p = fmaf(p, w, 0.00021858087f);
        p = fmaf(p, w, -0.00125372503f);
        p = fmaf(p, w, -0.00417768164f);
        p = fmaf(p, w, 0.246640727f);
        p = fmaf(p, w, 1.50140941f);
    } else {
        w = sqrtf(w) - 3.0f;
        p = -0.000200214257f;
        p = fmaf(p, w, 0.000100950558f);
        p = fmaf(p, w, 0.00134934322f);
        p = fmaf(p, w, -0.00367342844f);
        p = fmaf(p, w, 0.00573950773f);
        p = fmaf(p, w, -0.0076224613f);
        p = fmaf(p, w, 0.00943887047f);
        p = fmaf(p, w, 1.00167406f);
        p = fmaf(p, w, 2.83297682f);
    }
    return 1.41421356f * (p * r);
}

// 128-thread block sum (k3 only)
__device__ inline float block128_sum(float v, float* red) {
#pragma unroll
    for (int o = 32; o; o >>= 1) v += __shfl_down(v, o);
    __syncthreads();
    if ((threadIdx.x & 63) == 0) red[threadIdx.x >> 6] = v;
    __syncthreads();
    return red[0] + red[1];
}

// emit_q for 128-thread k3
__device__ void emit_q(float x, int bs,
                       const float* lnsg, const float* lnsb,
                       const float* wq, const float* bq,
                       const float* wkT, const float* bk,
                       float* qt, float* qc,
                       float* shA, float* red) {
    int t = threadIdx.x;
    float m = block128_sum(x, red) * (1.0f / 128.0f);
    float e = x - m;
    float var = block128_sum(e * e, red) * (1.0f / 128.0f);
    float inv = rsqrtf(var + 1e-5f);
    __syncthreads();
    shA[t] = fmaf(e * inv, lnsg[t], lnsb[t]);
    __syncthreads();
    float q = bq[t];
#pragma unroll 4
    for (int i = 0; i < 128; i++) q = fmaf(shA[i], wq[i * 128 + t], q);
    __syncthreads();
    shA[t] = q;
    __syncthreads();
    float a2 = 0.f;
#pragma unroll 4
    for (int j = 0; j < 128; j++) a2 = fmaf(wkT[j * 128 + t], shA[j], a2);
    const float scale = 0.08838834764831845f;  // 128^-0.5
    qt[bs * 128 + t] = a2 * scale;
    float pr = block128_sum(shA[t] * bk[t], red);
    if (t == 0) qc[bs] = pr * scale;
}

// ---------- K0: transpose gru weights + wk ----------

__global__ __launch_bounds__(256) void k0_transpose(
    const float* __restrict__ wih, const float* __restrict__ whh,
    const float* __restrict__ wk,
    float* __restrict__ wihT, float* __restrict__ whhT, float* __restrict__ wkT) {
    int idx = blockIdx.x * 256 + threadIdx.x;
    if (idx < 49152) {
        int d = idx / 384, g = idx % 384;
        wihT[idx] = wih[g * 128 + d];
    } else if (idx < 98304) {
        int o = idx - 49152;
        int d = o / 384, g = o % 384;
        whhT[o] = whh[g * 128 + d];
    } else if (idx < 114688) {
        int o = idx - 98304;
        int j = o >> 7, tcol = o & 127;
        wkT[o] = wk[tcol * 128 + j];
    }
}

// ---------- K1: fold weights, init slots, split-bf16 W ----------

__global__ __launch_bounds__(256) void k1_setup(
    const float* __restrict__ w0, const float* __restrict__ b0,
    const float* __restrict__ w1, const float* __restrict__ b1,
    const float* __restrict__ w2, const float* __restrict__ b2,
    const float* __restrict__ w3, const float* __restrict__ b3,
    const float* __restrict__ w4, const float* __restrict__ b4,
    const float* __restrict__ w5, const float* __restrict__ b5,
    const float* __restrict__ w7, const float* __restrict__ b7,
    const float* __restrict__ mu, const float* __restrict__ sg,
    float* __restrict__ Wh, float* __restrict__ bh, float* __restrict__ slots,
    u16* __restrict__ whiT, u16* __restrict__ wloT) {
    __shared__ float A[192], Bt[96], bb[64], bb2[32];
    __shared__ float stats[2];
    int t = threadIdx.x;
    for (int i = t; i < 192; i += 256) A[i] = w0[i];
    for (int i = t; i < 64; i += 256) bb[i] = b0[i];
    __syncthreads();
    const float* wl[5] = {w1, w2, w3, w4, w5};
    const float* bl[5] = {b1, b2, b3, b4, b5};
    int kin = 64;
    for (int l = 0; l < 5; l++) {
        const float* w = wl[l];
        const float* bias = bl[l];
        if (t < 96) {
            int i = t / 32, j = t % 32;
            float acc = 0.f;
            for (int k = 0; k < kin; k++) acc += A[i * kin + k] * w[k * 32 + j];
            Bt[i * 32 + j] = acc;
        } else if (t < 128) {
            int j = t - 96;
            float acc = bias[j];
            for (int k = 0; k < kin; k++) acc += bb[k] * w[k * 32 + j];
            bb2[j] = acc;
        }
        __syncthreads();
        if (t < 96) A[t] = Bt[t];
        if (t < 32) bb[t] = bb2[t];
        __syncthreads();
        kin = 32;
    }
    for (int idx = t; idx < 66 * 128; idx += 256) {
        int i = idx >> 7, j = idx & 127;
        float acc = w7[idx];
        if (i < 3) {
            for (int k = 0; k < 32; k++) acc += A[i * 32 + k] * w7[(66 + k) * 128 + j];
        }
        Wh[idx] = acc;
    }
    for (int j = t; j < 128; j += 256) {
        float acc = b7[j];
        for (int k = 0; k < 32; k++) acc += bb[k] * w7[(66 + k) * 128 + j];
        bh[j] = acc;
    }
    if (t == 0) {
        float s1 = 0.f, s2 = 0.f;
        for (int d = 0; d < 128; d++) { s1 += mu[d]; s2 += sg[d]; }
        float mmu = s1 / 128.f, msg = s2 / 128.f;
        float ss = 0.f;
        for (int d = 0; d < 128; d++) { float e = sg[d] - msg; ss += e * e; }
        stats[0] = mmu;
        stats[1] = sqrtf(64.f * ss / 8191.f);
    }
    __syncthreads();
    for (int idx = t; idx < 128 * 96; idx += 256) {
        int col = idx / 96, k = idx - col * 96;
        float v = (k < 66) ? Wh[k * 128 + col] : 0.f;
        u32 h = bfr1(v);
        float r = v - __uint_as_float(h << 16);
        whiT[idx] = (u16)h;
        wloT[idx] = (u16)bfr1(r);
    }
    float mean = stats[0], sd = stats[1];
    for (int p = t; p < 8192; p += 256) {
        u32 o0, o1;
        threefry42(0u, (u32)p, o0, o1);
        slots[p] = fmaf(sd, bits_to_normal(o0 ^ o1), mean);
    }
}

// ---------- K2: MFMA build of hln (bf16 row-major only) ----------

__global__ __launch_bounds__(256) void k2_hln(
    const float* __restrict__ inputs, const float* __restrict__ embed,
    const u16* __restrict__ whiT, const u16* __restrict__ wloT,
    const float* __restrict__ bh,
    const float* __restrict__ g, const float* __restrict__ bbias,
    u16* __restrict__ hlnb) {
    __shared__ __align__(16) char smem[51200];   // ebuf f32[128][100] / T u16[128][136]
    __shared__ float bhl[128], gl[128], bl[128];
    int t = threadIdx.x;
    float* ebuf = (float*)smem;
    size_t rbase = (size_t)blockIdx.x * 128;
    for (int idx = t; idx < 384; idx += 256)
        ebuf[(idx / 3) * 100 + (idx % 3)] = inputs[rbase * 3 + idx];
    for (int idx = t; idx < 128 * 63; idx += 256) {
        int r = idx / 63, i = idx - r * 63;
        ebuf[r * 100 + 3 + i] = embed[rbase * 63 + idx];
    }
    for (int idx = t; idx < 128 * 34; idx += 256) {
        int r = idx / 34, i = idx - r * 34;
        ebuf[r * 100 + 66 + i] = 0.f;
    }
    if (t < 128) { bhl[t] = bh[t]; gl[t] = g[t]; bl[t] = bbias[t]; }
    __syncthreads();

    int w = t >> 6, l = t & 63;
    int c16 = l & 15, g4 = l >> 4;
    int wr0 = w * 32;
    float bhc[8], gc[8], bc[8];
#pragma unroll
    for (int nt = 0; nt < 8; nt++) {
        bhc[nt] = bhl[nt * 16 + c16];
        gc[nt] = gl[nt * 16 + c16];
        bc[nt] = bl[nt * 16 + c16];
    }
    f32x4 acc[2][8];
#pragma unroll
    for (int mi = 0; mi < 2; mi++)
#pragma unroll
        for (int nt = 0; nt < 8; nt++)
            acc[mi][nt] = (f32x4){bhc[nt], bhc[nt], bhc[nt], bhc[nt]};

#pragma unroll
    for (int kc = 0; kc < 3; kc++) {
        bf16x8 ahi[2], alo[2];
#pragma unroll
        for (int mi = 0; mi < 2; mi++) {
            const float* ep = ebuf + (wr0 + mi * 16 + c16) * 100 + kc * 32 + g4 * 8;
            float4 a = *(const float4*)ep;
            float4 b = *(const float4*)(ep + 4);
            uint4 hw, lw;
            hw.x = packsplit(a.x, a.y, lw.x);
            hw.y = packsplit(a.z, a.w, lw.y);
            hw.z = packsplit(b.x, b.y, lw.z);
            hw.w = packsplit(b.z, b.w, lw.w);
            ahi[mi] = *(bf16x8*)&hw;
            alo[mi] = *(bf16x8*)&lw;
        }
#pragma unroll
        for (int nt = 0; nt < 8; nt++) {
            size_t boff = (size_t)(nt * 16 + c16) * 96 + kc * 32 + g4 * 8;
            uint4 bhw = *(const uint4*)(whiT + boff);
            uint4 blw = *(const uint4*)(wloT + boff);
            bf16x8 bhi = *(bf16x8*)&bhw;
            bf16x8 blo = *(bf16x8*)&blw;
#pragma unroll
            for (int mi = 0; mi < 2; mi++) {
                acc[mi][nt] = __builtin_amdgcn_mfma_f32_16x16x32_bf16(ahi[mi], bhi, acc[mi][nt], 0, 0, 0);
                acc[mi][nt] = __builtin_amdgcn_mfma_f32_16x16x32_bf16(ahi[mi], blo, acc[mi][nt], 0, 0, 0);
                acc[mi][nt] = __builtin_amdgcn_mfma_f32_16x16x32_bf16(alo[mi], bhi, acc[mi][nt], 0, 0, 0);
            }
        }
    }

    __syncthreads();
    u16* T = (u16*)smem;           // [128][136]
#pragma unroll
    for (int mi = 0; mi < 2; mi++) {
#pragma unroll
        for (int i = 0; i < 4; i++) {
            float s = 0.f;
#pragma unroll
            for (int nt = 0; nt < 8; nt++) s += acc[mi][nt][i];
            s += __shfl_xor(s, 1); s += __shfl_xor(s, 2);
            s += __shfl_xor(s, 4); s += __shfl_xor(s, 8);
            float m = s * (1.0f / 128.0f);
            float v = 0.f;
#pragma unroll
            for (int nt = 0; nt < 8; nt++) { float d = acc[mi][nt][i] - m; v = fmaf(d, d, v); }
            v += __shfl_xor(v, 1); v += __shfl_xor(v, 2);
            v += __shfl_xor(v, 4); v += __shfl_xor(v, 8);
            float inv = rsqrtf(v * (1.0f / 128.0f) + 1e-5f);
            int row = wr0 + mi * 16 + g4 * 4 + i;
#pragma unroll
            for (int nt = 0; nt < 8; nt++) {
                float val = fmaf((acc[mi][nt][i] - m) * inv, gc[nt], bc[nt]);
                T[row * 136 + nt * 16 + c16] = (u16)bfr1(val);
            }
        }
    }
    __syncthreads();
    {
        int r = t >> 1, hf = t & 1;
        const u16* Tr = T + r * 136 + hf * 64;
        u16* dst = hlnb + (rbase + r) * 128 + hf * 64;
#pragma unroll
        for (int j = 0; j < 8; j++) {
            uint4 v = *(const uint4*)(Tr + j * 8);
            *(uint4*)(dst + j * 8) = v;
        }
    }
}

// ---------- K3: initial q from slots ----------

__global__ __launch_bounds__(128) void k3_q(
    const float* __restrict__ slots,
    const float* __restrict__ lnsg, const float* __restrict__ lnsb,
    const float* __restrict__ wq, const float* __restrict__ bq,
    const float* __restrict__ wkT, const float* __restrict__ bk,
    float* __restrict__ qt, float* __restrict__ qc) {
    __shared__ float shA[128];
    __shared__ float red[2];
    int bs = blockIdx.x;
    float x = slots[bs * 128 + threadIdx.x];
    emit_q(x, bs, lnsg, lnsb, wq, bq, wkT, bk, qt, qc, shA, red);
}

// ---------- K4: MFMA attention, single-layout, LDS tile re-use ----------

__global__ __launch_bounds__(256) void k4_attn(
    const uint4* __restrict__ hlnb4,
    const float* __restrict__ qt, const float* __restrict__ qc,
    float* __restrict__ vecp, float* __restrict__ denp) {
    __shared__ __align__(16) u16 tiles[4][32 * 132];
    __shared__ __align__(16) u16 attnP[4][16 * 40];
    __shared__ __align__(16) float vlds[2][1024];
    __shared__ float dlds[4][8];
    int t = threadIdx.x;
    int w = t >> 6, l = t & 63;
    int blk = blockIdx.x;
    int b = blk >> 8, slab = blk & 255;
    size_t row0 = (size_t)b * N_ + (size_t)slab * 128 + (size_t)w * 32;
    int c16 = l & 15, g = l >> 4;
    u16* tw = tiles[w];

    bf16x8 qf[4];
#pragma unroll
    for (int kc = 0; kc < 4; kc++) {
        uint4 qu = {0u, 0u, 0u, 0u};
        if (c16 < 8) {
            const float* qp = qt + b * 1024 + c16 * 128 + kc * 32 + g * 8;
            float4 qa = *(const float4*)qp;
            float4 qb = *(const float4*)(qp + 4);
            qu.x = bfpack2(bfr1(qa.x), bfr1(qa.y));
            qu.y = bfpack2(bfr1(qa.z), bfr1(qa.w));
            qu.z = bfpack2(bfr1(qb.x), bfr1(qb.y));
            qu.w = bfpack2(bfr1(qb.z), bfr1(qb.w));
        }
        qf[kc] = *(bf16x8*)&qu;
    }
    float qcv = (c16 < 8) ? qc[b * 8 + c16] : 0.f;

    f32x4 dacc[2];
    dacc[0] = (f32x4){0.f, 0.f, 0.f, 0.f};
    dacc[1] = (f32x4){0.f, 0.f, 0.f, 0.f};
#pragma unroll
    for (int mt = 0; mt < 2; mt++) {
#pragma unroll
        for (int kc = 0; kc < 4; kc++) {
            uint4 au = hlnb4[(row0 + mt * 16 + c16) * 16 + kc * 4 + g];
            dacc[mt] = __builtin_amdgcn_mfma_f32_16x16x32_bf16(*(bf16x8*)&au, qf[kc], dacc[mt], 0, 0, 0);
            int off = (mt * 16 + c16) * 132 + kc * 32 + g * 8;
            uint2 lo; lo.x = au.x; lo.y = au.y;
            uint2 hi; hi.x = au.z; hi.y = au.w;
            *(uint2*)&tw[off] = lo;
            *(uint2*)&tw[off + 4] = hi;
        }
    }

    float denacc = 0.f;
#pragma unroll
    for (int mt = 0; mt < 2; mt++) {
        float pv[4];
#pragma unroll
        for (int r = 0; r < 4; r++) {
            float v = dacc[mt][r] + qcv;
            float mx = v;
            mx = fmaxf(mx, __shfl_xor(mx, 1));
            mx = fmaxf(mx, __shfl_xor(mx, 2));
            mx = fmaxf(mx, __shfl_xor(mx, 4));
            float e = __expf(v - mx);
            float ssum = e;
            ssum += __shfl_xor(ssum, 1);
            ssum += __shfl_xor(ssum, 2);
            ssum += __shfl_xor(ssum, 4);
            float a = (c16 < 8) ? fmaf(e, 1.0f / ssum, 1e-8f) : 0.f;
            pv[r] = a;
            denacc += a;
        }
        uint2 pw;
        pw.x = bfpack2(bfr1(pv[0]), bfr1(pv[1]));
        pw.y = bfpack2(bfr1(pv[2]), bfr1(pv[3]));
        *(uint2*)&attnP[w][c16 * 40 + mt * 16 + g * 4] = pw;
    }
    denacc += __shfl_xor(denacc, 16);
    denacc += __shfl_xor(denacc, 32);
    if (l < 8) dlds[w][l] = denacc;

    uint4 afu = *(const uint4*)&attnP[w][c16 * 40 + g * 8];
    bf16x8 af = *(bf16x8*)&afu;
    f32x4 uacc[8];
#pragma unroll
    for (int nt = 0; nt < 8; nt++) uacc[nt] = (f32x4){0.f, 0.f, 0.f, 0.f};
#pragma unroll
    for (int nt = 0; nt < 8; nt++) {
        const u16* tp = tw + nt * 16 + c16;
        u32 w0 = (u32)tp[(g * 8 + 0) * 132] | ((u32)tp[(g * 8 + 1) * 132] << 16);
        u32 w1 = (u32)tp[(g * 8 + 2) * 132] | ((u32)tp[(g * 8 + 3) * 132] << 16);
        u32 w2 = (u32)tp[(g * 8 + 4) * 132] | ((u32)tp[(g * 8 + 5) * 132] << 16);
        u32 w3 = (u32)tp[(g * 8 + 6) * 132] | ((u32)tp[(g * 8 + 7) * 132] << 16);
        uint4 bu; bu.x = w0; bu.y = w1; bu.z = w2; bu.w = w3;
        uacc[nt] = __builtin_amdgcn_mfma_f32_16x16x32_bf16(af, *(bf16x8*)&bu, uacc[nt], 0, 0, 0);
    }
    if (w < 2 && g < 2) {
#pragma unroll
        for (int nt = 0; nt < 8; nt++)
#pragma unroll
            for (int r = 0; r < 4; r++)
                vlds[w][(g * 4 + r) * 128 + nt * 16 + c16] = uacc[nt][r];
    }
    __syncthreads();
    if (w >= 2 && g < 2) {
#pragma unroll
        for (int nt = 0; nt < 8; nt++)
#pragma unroll
            for (int r = 0; r < 4; r++)
                vlds[w - 2][(g * 4 + r) * 128 + nt * 16 + c16] += uacc[nt][r];
    }
    __syncthreads();
    float* vout = vecp + ((size_t)blk << 10);
#pragma unroll
    for (int rep = 0; rep < 4; rep++) {
        int o = rep * 256 + t;
        vout[o] = vlds[0][o] + vlds[1][o];
    }
    if (t < 8) denp[blk * 8 + t] = dlds[0][t] + dlds[1][t] + dlds[2][t] + dlds[3][t];
}

// ---------- K5: 512-thread parallel update ----------
// thread = (d = t&127, qq = t>>7). Every 128-dot = 32-iter partial + tree.

__device__ inline float sum512(float v, float* red8) {
#pragma unroll
    for (int o = 32; o; o >>= 1) v += __shfl_down(v, o);
    __syncthreads();
    if ((threadIdx.x & 63) == 0) red8[threadIdx.x >> 6] = v;
    __syncthreads();
    float s = 0.f;
#pragma unroll
    for (int i = 0; i < 8; i++) s += red8[i];
    return s;
}

__device__ inline float reduce4(float part, float* praw, int qq, int d) {
    __syncthreads();
    praw[qq * 128 + d] = part;
    __syncthreads();
    return praw[d] + praw[128 + d] + praw[256 + d] + praw[384 + d];
}

__global__ __launch_bounds__(512) void k5_update(
    const float* __restrict__ vecp, const float* __restrict__ denp,
    const float* __restrict__ wv, const float* __restrict__ bv,
    const float* __restrict__ wihT, const float* __restrict__ whhT,
    const float* __restrict__ bih, const float* __restrict__ bhh,
    const float* __restrict__ lnfg, const float* __restrict__ lnfb,
    const float* __restrict__ m1w, const float* __restrict__ m1b,
    const float* __restrict__ m2w, const float* __restrict__ m2b,
    float* __restrict__ slots,
    const float* __restrict__ lnsg, const float* __restrict__ lnsb,
    const float* __restrict__ wq, const float* __restrict__ bq,
    const float* __restrict__ wkT, const float* __restrict__ bk,
    float* __restrict__ qt, float* __restrict__ qc,
    float* __restrict__ out, int compute_q, int write_out) {
    __shared__ float sA[128], sB[128], sC[128], sH[128], sQ[128];
    __shared__ float praw[512];
    __shared__ float red8[8];
    __shared__ float gsc[6][512];
    int t = threadIdx.x;
    int bs = blockIdx.x;
    int b = bs >> 3, slot = bs & 7;
    int d = t & 127, qq = t >> 7;

    // den: 256 slab partials
    float dvp = (t < 256) ? denp[((size_t)(b * 256) + t) * 8 + slot] : 0.f;
    float dv = sum512(dvp, red8);

    // vec: 64 slabs per quarter
    float vs = 0.f;
    const float* vp0 = vecp + (((size_t)(b * 256 + qq * 64)) << 10) + slot * 128 + d;
#pragma unroll 8
    for (int s = 0; s < 64; s++) vs += vp0[(size_t)s << 10];
    float vtot = reduce4(vs, praw, qq, d);
    if (qq == 0) { sA[d] = vtot / dv; sC[d] = slots[bs * 128 + d]; }
    __syncthreads();

    // upd = sA @ wv + bv
    float up = 0.f;
    {
        const float* wvp = wv + (size_t)(qq * 32) * 128 + d;
#pragma unroll 8
        for (int i = 0; i < 32; i++) up = fmaf(sA[qq * 32 + i], wvp[i * 128], up);
    }
    float updt = reduce4(up, praw, qq, d) + bv[d];
    if (qq == 0) sB[d] = updt;
    __syncthreads();

    // GRU gates: 6 partial arrays, one sync
#pragma unroll 1
    for (int gx = 0; gx < 3; gx++) {
        int g = gx * 128 + d;
        float ap = 0.f, hp = 0.f;
        const float* wi = wihT + (size_t)(qq * 32) * 384 + g;
        const float* wh = whhT + (size_t)(qq * 32) * 384 + g;
#pragma unroll 8
        for (int i = 0; i < 32; i++) {
            ap = fmaf(sB[qq * 32 + i], wi[i * 384], ap);
            hp = fmaf(sC[qq * 32 + i], wh[i * 384], hp);
        }
        gsc[gx * 2][t] = ap;
        gsc[gx * 2 + 1][t] = hp;
    }
    __syncthreads();
    float gi0 = gsc[0][d] + gsc[0][128 + d] + gsc[0][256 + d] + gsc[0][384 + d] + bih[d];
    float gh0 = gsc[1][d] + gsc[1][128 + d] + gsc[1][256 + d] + gsc[1][384 + d] + bhh[d];
    float gi1 = gsc[2][d] + gsc[2][128 + d] + gsc[2][256 + d] + gsc[2][384 + d] + bih[128 + d];
    float gh1 = gsc[3][d] + gsc[3][128 + d] + gsc[3][256 + d] + gsc[3][384 + d] + bhh[128 + d];
    float gi2 = gsc[4][d] + gsc[4][128 + d] + gsc[4][256 + d] + gsc[4][384 + d] + bih[256 + d];
    float gh2 = gsc[5][d] + gsc[5][128 + d] + gsc[5][256 + d] + gsc[5][384 + d] + bhh[256 + d];
    float rg = 1.f / (1.f + expf(-(gi0 + gh0)));
    float zg = 1.f / (1.f + expf(-(gi1 + gh1)));
    float ng = tanhf(fmaf(rg, gh2, gi2));
    float hnew = (1.f - zg) * ng + zg * sC[d];
    __syncthreads();
    if (qq == 0) sH[d] = hnew;
    __syncthreads();

    // LN_ff over sH
    float xh = (t < 128) ? sH[t] : 0.f;
    float mh = sum512(xh, red8) * (1.0f / 128.0f);
    float eh = xh - mh;
    float vh = sum512((t < 128) ? eh * eh : 0.f, red8) * (1.0f / 128.0f);
    float invh = rsqrtf(vh + 1e-5f);
    __syncthreads();
    if (t < 128) sA[t] = fmaf(eh * invh, lnfg[t], lnfb[t]);
    __syncthreads();

    // m1
    float p1 = 0.f;
    {
        const float* m1p = m1w + (size_t)(qq * 32) * 128 + d;
#pragma unroll 8
        for (int i = 0; i < 32; i++) p1 = fmaf(sA[qq * 32 + i], m1p[i * 128], p1);
    }
    float m1v = reduce4(p1, praw, qq, d) + m1b[d];
    if (qq == 0) sB[d] = m1v;
    __syncthreads();

    // m2 + residual
    float p2 = 0.f;
    {
        const float* m2p = m2w + (size_t)(qq * 32) * 128 + d;
#pragma unroll 8
        for (int i = 0; i < 32; i++) p2 = fmaf(sB[qq * 32 + i], m2p[i * 128], p2);
    }
    float m2v = reduce4(p2, praw, qq, d) + m2b[d];
    float snew = sH[d] + m2v;
    __syncthreads();
    if (qq == 0) {
        slots[bs * 128 + d] = snew;
        if (write_out) out[bs * 128 + d] = snew;
        sH[d] = snew;
    }
    __syncthreads();

    if (compute_q) {
        // LN_sl over snew
        float xs = (t < 128) ? sH[t] : 0.f;
        float ms = sum512(xs, red8) * (1.0f / 128.0f);
        float es = xs - ms;
        float vs2 = sum512((t < 128) ? es * es : 0.f, red8) * (1.0f / 128.0f);
        float invs = rsqrtf(vs2 + 1e-5f);
        __syncthreads();
        if (t < 128) sA[t] = fmaf(es * invs, lnsg[t], lnsb[t]);
        __syncthreads();
        // q = sA @ wq + bq
        float pq = 0.f;
        {
            const float* wqp = wq + (size_t)(qq * 32) * 128 + d;
#pragma unroll 8
            for (int i = 0; i < 32; i++) pq = fmaf(sA[qq * 32 + i], wqp[i * 128], pq);
        }
        float qv = reduce4(pq, praw, qq, d) + bq[d];
        if (qq == 0) sQ[d] = qv;
        __syncthreads();
        // a2 = wkT . q
        float pa = 0.f;
        {
            const float* wkp = wkT + (size_t)(qq * 32) * 128 + d;
#pragma unroll 8
            for (int j = 0; j < 32; j++) pa = fmaf(wkp[j * 128], sQ[qq * 32 + j], pa);
        }
        const float scale = 0.08838834764831845f;
        float a2 = reduce4(pa, praw, qq, d) * scale;
        if (qq == 0) qt[bs * 128 + d] = a2;
        float xpr = (t < 128) ? sQ[t] * bk[t] : 0.f;
        float pr = sum512(xpr, red8);
        if (t == 0) qc[bs] = pr * scale;
    }
}

// ---------- launch ----------

extern "C" void kernel_launch(void* const* d_in, const int* in_sizes, int n_in,
                              void* d_out, int out_size, void* d_ws, size_t ws_size,
                              hipStream_t stream) {
    const float* inputs = (const float*)d_in[0];
    const float* embed  = (const float*)d_in[1];
    const float* mu     = (const float*)d_in[2];
    const float* sg     = (const float*)d_in[3];
    const float* w0 = (const float*)d_in[4];  const float* b0 = (const float*)d_in[5];
    const float* w1 = (const float*)d_in[6];  const float* b1 = (const float*)d_in[7];
    const float* w2 = (const float*)d_in[8];  const float* b2 = (const float*)d_in[9];
    const float* w3 = (const float*)d_in[10]; const float* b3 = (const float*)d_in[11];
    const float* w4 = (const float*)d_in[12]; const float* b4 = (const float*)d_in[13];
    const float* w5 = (const float*)d_in[14]; const float* b5 = (const float*)d_in[15];
    const float* w7 = (const float*)d_in[16]; const float* b7 = (const float*)d_in[17];
    const float* wq = (const float*)d_in[18]; const float* bq = (const float*)d_in[19];
    const float* wk = (const float*)d_in[20]; const float* bk = (const float*)d_in[21];
    const float* wv = (const float*)d_in[22]; const float* bv = (const float*)d_in[23];
    const float* ln_in_g = (const float*)d_in[24]; const float* ln_in_b = (const float*)d_in[25];
    const float* ln_sl_g = (const float*)d_in[26]; const float* ln_sl_b = (const float*)d_in[27];
    const float* ln_ff_g = (const float*)d_in[28]; const float* ln_ff_b = (const float*)d_in[29];
    const float* gwih = (const float*)d_in[30]; const float* gwhh = (const float*)d_in[31];
    const float* gbih = (const float*)d_in[32]; const float* gbhh = (const float*)d_in[33];
    const float* m1w = (const float*)d_in[34]; const float* m1b = (const float*)d_in[35];
    const float* m2w = (const float*)d_in[36]; const float* m2b = (const float*)d_in[37];

    char* ws = (char*)d_ws;
    u16* hlnb = (u16*)ws;
    size_t off = (size_t)NB_ * 128 * 2;  // 64 MB bf16 hln row-major
    float* Wh    = (float*)(ws + off); off += 66 * 128 * 4;
    float* bh    = (float*)(ws + off); off += 128 * 4;
    float* slots = (float*)(ws + off); off += 64 * 128 * 4;
    float* qt    = (float*)(ws + off); off += 64 * 128 * 4;
    float* qc    = (float*)(ws + off); off += 64 * 4;
    float* vecp  = (float*)(ws + off); off += (size_t)2048 * 1024 * 4;  // 8 MB
    float* denp  = (float*)(ws + off); off += 2048 * 8 * 4;
    float* wihT  = (float*)(ws + off); off += 384 * 128 * 4;
    float* whhT  = (float*)(ws + off); off += 384 * 128 * 4;
    float* wkT   = (float*)(ws + off); off += 128 * 128 * 4;
    u16* whiT    = (u16*)(ws + off); off += 128 * 96 * 2;
    u16* wloT    = (u16*)(ws + off); off += 128 * 96 * 2;

    k0_transpose<<<448, 256, 0, stream>>>(gwih, gwhh, wk, wihT, whhT, wkT);
    k1_setup<<<1, 256, 0, stream>>>(w0, b0, w1, b1, w2, b2, w3, b3, w4, b4, w5, b5,
                                    w7, b7, mu, sg, Wh, bh, slots, whiT, wloT);
    k2_hln<<<NB_ / 128, 256, 0, stream>>>(inputs, embed, whiT, wloT, bh,
                                          ln_in_g, ln_in_b, hlnb);
    k3_q<<<64, 128, 0, stream>>>(slots, ln_sl_g, ln_sl_b, wq, bq, wkT, bk, qt, qc);
    for (int it = 0; it < 3; it++) {
        k4_attn<<<2048, 256, 0, stream>>>((const uint4*)hlnb, qt, qc, vecp, denp);
        k5_update<<<64, 512, 0, stream>>>(vecp, denp, wv, bv, wihT, whhT, gbih, gbhh,
                                          ln_ff_g, ln_ff_b, m1w, m1b, m2w, m2b, slots,
                                          ln_sl_g, ln_sl_b, wq, bq, wkT, bk, qt, qc,
                                          (float*)d_out, (it < 2) ? 1 : 0, (it == 2) ? 1 : 0);
    }
}

// Round 17
// 273.933 us; speedup vs baseline: 1.7702x; 1.0214x over previous
//
#include <hip/hip_runtime.h>

// SlotAttention fused implementation (bf16 hln, single layout, MFMA).
//   - 6-layer linear stack folded into effective 66->128 affine (Wh, bh).
//   - k,v folded out of N:  q.k_n = (wk@q).hln_n + q.bk ;
//     updates = (sum attn*hln)/den @ wv + bv
//   - hln bf16 row-major [NB][128] only (64 MB, L3-resident).
//   - slot init: JAX partitionable threefry: bits[i] = o0^o1, counter (0,i).
//   - k2: single-bf16 MFMA GEMM; E pre-converted to bf16 in LDS (direct
//     ds_read_b128 A-frags), B = whiT bf16 [128][96] (L2-hot). 4 blocks/CU.
//   - k4: 2048 blocks x 4 waves x 32 rows; per-slab partials (no atomics).
//   - k5: 512 threads; GEMVs as 32-iter partials + LDS tree reduce.

#define B_  8
#define N_  32768
#define NB_ (B_ * N_)   // 262144 rows
#define D_  128
#define S_  8

typedef unsigned int u32;
typedef unsigned short u16;
typedef __attribute__((ext_vector_type(8))) short bf16x8;
typedef __attribute__((ext_vector_type(4))) float f32x4;

__device__ inline u32 bfr1(float x) {  // f32 -> bf16 (RNE)
    u32 u = __float_as_uint(x);
    return (u + 0x7FFFu + ((u >> 16) & 1u)) >> 16;
}
__device__ inline u32 bfpack2(u32 lo, u32 hi) { return lo | (hi << 16); }

// threefry2x32, key = (0, 42)
__device__ inline void threefry42(u32 c0, u32 c1, u32& o0, u32& o1) {
    const u32 k0 = 0u, k1 = 42u, k2 = 0x1BD11BDAu ^ 0u ^ 42u;
    const u32 ks[3] = {k0, k1, k2};
    u32 x0 = c0 + k0, x1 = c1 + k1;
    const int rA[4] = {13, 15, 26, 6}, rB[4] = {17, 29, 16, 24};
#pragma unroll
    for (int i = 0; i < 5; i++) {
#pragma unroll
        for (int k = 0; k < 4; k++) {
            int r = (i & 1) ? rB[k] : rA[k];
            x0 += x1;
            x1 = (x1 << r) | (x1 >> (32 - r));
            x1 ^= x0;
        }
        x0 += ks[(i + 1) % 3];
        x1 += ks[(i + 2) % 3] + (u32)(i + 1);
    }
    o0 = x0; o1 = x1;
}

// jax uniform(-0.99999994, 1) -> sqrt(2)*erfinv
__device__ inline float bits_to_normal(u32 b) {
    float f = __uint_as_float((b >> 9) | 0x3f800000u) - 1.0f;
    const float lo = -0.99999994f;
    float r = fmaxf(lo, f * 1.99999994f + lo);
    float w = -log1pf(-r * r);
    float p;
    if (w < 5.0f) {
        w -= 2.5f;
        p = 2.81022636e-08f;
        p = fmaf(p, w, 3.43273939e-07f);
        p = fmaf(p, w, -3.5233877e-06f);
        p = fmaf(p, w, -4.39150654e-06f);
        p = fmaf(p, w, 0.00021858087f);
        p = fmaf(p, w, -0.00125372503f);
        p = fmaf(p, w, -0.00417768164f);
        p = fmaf(p, w, 0.246640727f);
        p = fmaf(p, w, 1.50140941f);
    } else {
        w = sqrtf(w) - 3.0f;
        p = -0.000200214257f;
        p = fmaf(p, w, 0.000100950558f);
        p = fmaf(p, w, 0.00134934322f);
        p = fmaf(p, w, -0.00367342844f);
        p = fmaf(p, w, 0.00573950773f);
        p = fmaf(p, w, -0.0076224613f);
        p = fmaf(p, w, 0.00943887047f);
        p = fmaf(p, w, 1.00167406f);
        p = fmaf(p, w, 2.83297682f);
    }
    return 1.41421356f * (p * r);
}

// 128-thread block sum (k3 only)
__device__ inline float block128_sum(float v, float* red) {
#pragma unroll
    for (int o = 32; o; o >>= 1) v += __shfl_down(v, o);
    __syncthreads();
    if ((threadIdx.x & 63) == 0) red[threadIdx.x >> 6] = v;
    __syncthreads();
    return red[0] + red[1];
}

// emit_q for 128-thread k3
__device__ void emit_q(float x, int bs,
                       const float* lnsg, const float* lnsb,
                       const float* wq, const float* bq,
                       const float* wkT, const float* bk,
                       float* qt, float* qc,
                       float* shA, float* red) {
    int t = threadIdx.x;
    float m = block128_sum(x, red) * (1.0f / 128.0f);
    float e = x - m;
    float var = block128_sum(e * e, red) * (1.0f / 128.0f);
    float inv = rsqrtf(var + 1e-5f);
    __syncthreads();
    shA[t] = fmaf(e * inv, lnsg[t], lnsb[t]);
    __syncthreads();
    float q = bq[t];
#pragma unroll 4
    for (int i = 0; i < 128; i++) q = fmaf(shA[i], wq[i * 128 + t], q);
    __syncthreads();
    shA[t] = q;
    __syncthreads();
    float a2 = 0.f;
#pragma unroll 4
    for (int j = 0; j < 128; j++) a2 = fmaf(wkT[j * 128 + t], shA[j], a2);
    const float scale = 0.08838834764831845f;  // 128^-0.5
    qt[bs * 128 + t] = a2 * scale;
    float pr = block128_sum(shA[t] * bk[t], red);
    if (t == 0) qc[bs] = pr * scale;
}

// ---------- K0: transpose gru weights + wk ----------

__global__ __launch_bounds__(256) void k0_transpose(
    const float* __restrict__ wih, const float* __restrict__ whh,
    const float* __restrict__ wk,
    float* __restrict__ wihT, float* __restrict__ whhT, float* __restrict__ wkT) {
    int idx = blockIdx.x * 256 + threadIdx.x;
    if (idx < 49152) {
        int d = idx / 384, g = idx % 384;
        wihT[idx] = wih[g * 128 + d];
    } else if (idx < 98304) {
        int o = idx - 49152;
        int d = o / 384, g = o % 384;
        whhT[o] = whh[g * 128 + d];
    } else if (idx < 114688) {
        int o = idx - 98304;
        int j = o >> 7, tcol = o & 127;
        wkT[o] = wk[tcol * 128 + j];
    }
}

// ---------- K1: fold weights, init slots, bf16 W ----------

__global__ __launch_bounds__(256) void k1_setup(
    const float* __restrict__ w0, const float* __restrict__ b0,
    const float* __restrict__ w1, const float* __restrict__ b1,
    const float* __restrict__ w2, const float* __restrict__ b2,
    const float* __restrict__ w3, const float* __restrict__ b3,
    const float* __restrict__ w4, const float* __restrict__ b4,
    const float* __restrict__ w5, const float* __restrict__ b5,
    const float* __restrict__ w7, const float* __restrict__ b7,
    const float* __restrict__ mu, const float* __restrict__ sg,
    float* __restrict__ Wh, float* __restrict__ bh, float* __restrict__ slots,
    u16* __restrict__ whiT) {
    __shared__ float A[192], Bt[96], bb[64], bb2[32];
    __shared__ float stats[2];
    int t = threadIdx.x;
    for (int i = t; i < 192; i += 256) A[i] = w0[i];
    for (int i = t; i < 64; i += 256) bb[i] = b0[i];
    __syncthreads();
    const float* wl[5] = {w1, w2, w3, w4, w5};
    const float* bl[5] = {b1, b2, b3, b4, b5};
    int kin = 64;
    for (int l = 0; l < 5; l++) {
        const float* w = wl[l];
        const float* bias = bl[l];
        if (t < 96) {
            int i = t / 32, j = t % 32;
            float acc = 0.f;
            for (int k = 0; k < kin; k++) acc += A[i * kin + k] * w[k * 32 + j];
            Bt[i * 32 + j] = acc;
        } else if (t < 128) {
            int j = t - 96;
            float acc = bias[j];
            for (int k = 0; k < kin; k++) acc += bb[k] * w[k * 32 + j];
            bb2[j] = acc;
        }
        __syncthreads();
        if (t < 96) A[t] = Bt[t];
        if (t < 32) bb[t] = bb2[t];
        __syncthreads();
        kin = 32;
    }
    for (int idx = t; idx < 66 * 128; idx += 256) {
        int i = idx >> 7, j = idx & 127;
        float acc = w7[idx];
        if (i < 3) {
            for (int k = 0; k < 32; k++) acc += A[i * 32 + k] * w7[(66 + k) * 128 + j];
        }
        Wh[idx] = acc;
    }
    for (int j = t; j < 128; j += 256) {
        float acc = b7[j];
        for (int k = 0; k < 32; k++) acc += bb[k] * w7[(66 + k) * 128 + j];
        bh[j] = acc;
    }
    if (t == 0) {
        float s1 = 0.f, s2 = 0.f;
        for (int d = 0; d < 128; d++) { s1 += mu[d]; s2 += sg[d]; }
        float mmu = s1 / 128.f, msg = s2 / 128.f;
        float ss = 0.f;
        for (int d = 0; d < 128; d++) { float e = sg[d] - msg; ss += e * e; }
        stats[0] = mmu;
        stats[1] = sqrtf(64.f * ss / 8191.f);
    }
    __syncthreads();
    for (int idx = t; idx < 128 * 96; idx += 256) {
        int col = idx / 96, k = idx - col * 96;
        float v = (k < 66) ? Wh[k * 128 + col] : 0.f;
        whiT[idx] = (u16)bfr1(v);
    }
    float mean = stats[0], sd = stats[1];
    for (int p = t; p < 8192; p += 256) {
        u32 o0, o1;
        threefry42(0u, (u32)p, o0, o1);
        slots[p] = fmaf(sd, bits_to_normal(o0 ^ o1), mean);
    }
}

// ---------- K2: single-bf16 MFMA build of hln ----------
// E staged as bf16 u16[128][104] (stride 208 B, b128-aligned, 2-way banks).
// A-frags = direct ds_read_b128. B = whiT from L2. 48 MFMA/wave.

__global__ __launch_bounds__(256) void k2_hln(
    const float* __restrict__ inputs, const float* __restrict__ embed,
    const u16* __restrict__ whiT, const float* __restrict__ bh,
    const float* __restrict__ g, const float* __restrict__ bbias,
    u16* __restrict__ hlnb) {
    __shared__ __align__(16) char smem[34816];  // ebuf u16[128][104]=26624 / T u16[128][136]=34816
    __shared__ float bhl[128], gl[128], bl[128];
    int t = threadIdx.x;
    u16* ebuf = (u16*)smem;
    size_t rbase = (size_t)blockIdx.x * 128;
    for (int idx = t; idx < 384; idx += 256)
        ebuf[(idx / 3) * 104 + (idx % 3)] = (u16)bfr1(inputs[rbase * 3 + idx]);
    for (int idx = t; idx < 128 * 63; idx += 256) {
        int r = idx / 63, i = idx - r * 63;
        ebuf[r * 104 + 3 + i] = (u16)bfr1(embed[rbase * 63 + idx]);
    }
    for (int idx = t; idx < 128 * 30; idx += 256) {
        int r = idx / 30, i = idx - r * 30;
        ebuf[r * 104 + 66 + i] = 0;
    }
    if (t < 128) { bhl[t] = bh[t]; gl[t] = g[t]; bl[t] = bbias[t]; }
    __syncthreads();

    int w = t >> 6, l = t & 63;
    int c16 = l & 15, g4 = l >> 4;
    int wr0 = w * 32;
    float bhc[8], gc[8], bc[8];
#pragma unroll
    for (int nt = 0; nt < 8; nt++) {
        bhc[nt] = bhl[nt * 16 + c16];
        gc[nt] = gl[nt * 16 + c16];
        bc[nt] = bl[nt * 16 + c16];
    }
    f32x4 acc[2][8];
#pragma unroll
    for (int mi = 0; mi < 2; mi++)
#pragma unroll
        for (int nt = 0; nt < 8; nt++)
            acc[mi][nt] = (f32x4){bhc[nt], bhc[nt], bhc[nt], bhc[nt]};

#pragma unroll
    for (int kc = 0; kc < 3; kc++) {
        bf16x8 a0 = *(const bf16x8*)&ebuf[(wr0 + c16) * 104 + kc * 32 + g4 * 8];
        bf16x8 a1 = *(const bf16x8*)&ebuf[(wr0 + 16 + c16) * 104 + kc * 32 + g4 * 8];
#pragma unroll
        for (int nt = 0; nt < 8; nt++) {
            uint4 bw = *(const uint4*)(whiT + (size_t)(nt * 16 + c16) * 96 + kc * 32 + g4 * 8);
            bf16x8 bf = *(bf16x8*)&bw;
            acc[0][nt] = __builtin_amdgcn_mfma_f32_16x16x32_bf16(a0, bf, acc[0][nt], 0, 0, 0);
            acc[1][nt] = __builtin_amdgcn_mfma_f32_16x16x32_bf16(a1, bf, acc[1][nt], 0, 0, 0);
        }
    }

    __syncthreads();
    u16* T = (u16*)smem;           // [128][136]
#pragma unroll
    for (int mi = 0; mi < 2; mi++) {
#pragma unroll
        for (int i = 0; i < 4; i++) {
            float s = 0.f;
#pragma unroll
            for (int nt = 0; nt < 8; nt++) s += acc[mi][nt][i];
            s += __shfl_xor(s, 1); s += __shfl_xor(s, 2);
            s += __shfl_xor(s, 4); s += __shfl_xor(s, 8);
            float m = s * (1.0f / 128.0f);
            float v = 0.f;
#pragma unroll
            for (int nt = 0; nt < 8; nt++) { float d = acc[mi][nt][i] - m; v = fmaf(d, d, v); }
            v += __shfl_xor(v, 1); v += __shfl_xor(v, 2);
            v += __shfl_xor(v, 4); v += __shfl_xor(v, 8);
            float inv = rsqrtf(v * (1.0f / 128.0f) + 1e-5f);
            int row = wr0 + mi * 16 + g4 * 4 + i;
#pragma unroll
            for (int nt = 0; nt < 8; nt++) {
                float val = fmaf((acc[mi][nt][i] - m) * inv, gc[nt], bc[nt]);
                T[row * 136 + nt * 16 + c16] = (u16)bfr1(val);
            }
        }
    }
    __syncthreads();
    {
        int r = t >> 1, hf = t & 1;
        const u16* Tr = T + r * 136 + hf * 64;
        u16* dst = hlnb + (rbase + r) * 128 + hf * 64;
#pragma unroll
        for (int j = 0; j < 8; j++) {
            uint4 v = *(const uint4*)(Tr + j * 8);
            *(uint4*)(dst + j * 8) = v;
        }
    }
}

// ---------- K3: initial q from slots ----------

__global__ __launch_bounds__(128) void k3_q(
    const float* __restrict__ slots,
    const float* __restrict__ lnsg, const float* __restrict__ lnsb,
    const float* __restrict__ wq, const float* __restrict__ bq,
    const float* __restrict__ wkT, const float* __restrict__ bk,
    float* __restrict__ qt, float* __restrict__ qc) {
    __shared__ float shA[128];
    __shared__ float red[2];
    int bs = blockIdx.x;
    float x = slots[bs * 128 + threadIdx.x];
    emit_q(x, bs, lnsg, lnsb, wq, bq, wkT, bk, qt, qc, shA, red);
}

// ---------- K4: MFMA attention, single-layout, LDS tile re-use ----------

__global__ __launch_bounds__(256) void k4_attn(
    const uint4* __restrict__ hlnb4,
    const float* __restrict__ qt, const float* __restrict__ qc,
    float* __restrict__ vecp, float* __restrict__ denp) {
    __shared__ __align__(16) u16 tiles[4][32 * 132];
    __shared__ __align__(16) u16 attnP[4][16 * 40];
    __shared__ __align__(16) float vlds[2][1024];
    __shared__ float dlds[4][8];
    int t = threadIdx.x;
    int w = t >> 6, l = t & 63;
    int blk = blockIdx.x;
    int b = blk >> 8, slab = blk & 255;
    size_t row0 = (size_t)b * N_ + (size_t)slab * 128 + (size_t)w * 32;
    int c16 = l & 15, g = l >> 4;
    u16* tw = tiles[w];

    bf16x8 qf[4];
#pragma unroll
    for (int kc = 0; kc < 4; kc++) {
        uint4 qu = {0u, 0u, 0u, 0u};
        if (c16 < 8) {
            const float* qp = qt + b * 1024 + c16 * 128 + kc * 32 + g * 8;
            float4 qa = *(const float4*)qp;
            float4 qb = *(const float4*)(qp + 4);
            qu.x = bfpack2(bfr1(qa.x), bfr1(qa.y));
            qu.y = bfpack2(bfr1(qa.z), bfr1(qa.w));
            qu.z = bfpack2(bfr1(qb.x), bfr1(qb.y));
            qu.w = bfpack2(bfr1(qb.z), bfr1(qb.w));
        }
        qf[kc] = *(bf16x8*)&qu;
    }
    float qcv = (c16 < 8) ? qc[b * 8 + c16] : 0.f;

    f32x4 dacc[2];
    dacc[0] = (f32x4){0.f, 0.f, 0.f, 0.f};
    dacc[1] = (f32x4){0.f, 0.f, 0.f, 0.f};
#pragma unroll
    for (int mt = 0; mt < 2; mt++) {
#pragma unroll
        for (int kc = 0; kc < 4; kc++) {
            uint4 au = hlnb4[(row0 + mt * 16 + c16) * 16 + kc * 4 + g];
            dacc[mt] = __builtin_amdgcn_mfma_f32_16x16x32_bf16(*(bf16x8*)&au, qf[kc], dacc[mt], 0, 0, 0);
            int off = (mt * 16 + c16) * 132 + kc * 32 + g * 8;
            uint2 lo; lo.x = au.x; lo.y = au.y;
            uint2 hi; hi.x = au.z; hi.y = au.w;
            *(uint2*)&tw[off] = lo;
            *(uint2*)&tw[off + 4] = hi;
        }
    }

    float denacc = 0.f;
#pragma unroll
    for (int mt = 0; mt < 2; mt++) {
        float pv[4];
#pragma unroll
        for (int r = 0; r < 4; r++) {
            float v = dacc[mt][r] + qcv;
            float mx = v;
            mx = fmaxf(mx, __shfl_xor(mx, 1));
            mx = fmaxf(mx, __shfl_xor(mx, 2));
            mx = fmaxf(mx, __shfl_xor(mx, 4));
            float e = __expf(v - mx);
            float ssum = e;
            ssum += __shfl_xor(ssum, 1);
            ssum += __shfl_xor(ssum, 2);
            ssum += __shfl_xor(ssum, 4);
            float a = (c16 < 8) ? fmaf(e, 1.0f / ssum, 1e-8f) : 0.f;
            pv[r] = a;
            denacc += a;
        }
        uint2 pw;
        pw.x = bfpack2(bfr1(pv[0]), bfr1(pv[1]));
        pw.y = bfpack2(bfr1(pv[2]), bfr1(pv[3]));
        *(uint2*)&attnP[w][c16 * 40 + mt * 16 + g * 4] = pw;
    }
    denacc += __shfl_xor(denacc, 16);
    denacc += __shfl_xor(denacc, 32);
    if (l < 8) dlds[w][l] = denacc;

    uint4 afu = *(const uint4*)&attnP[w][c16 * 40 + g * 8];
    bf16x8 af = *(bf16x8*)&afu;
    f32x4 uacc[8];
#pragma unroll
    for (int nt = 0; nt < 8; nt++) uacc[nt] = (f32x4){0.f, 0.f, 0.f, 0.f};
#pragma unroll
    for (int nt = 0; nt < 8; nt++) {
        const u16* tp = tw + nt * 16 + c16;
        u32 w0 = (u32)tp[(g * 8 + 0) * 132] | ((u32)tp[(g * 8 + 1) * 132] << 16);
        u32 w1 = (u32)tp[(g * 8 + 2) * 132] | ((u32)tp[(g * 8 + 3) * 132] << 16);
        u32 w2 = (u32)tp[(g * 8 + 4) * 132] | ((u32)tp[(g * 8 + 5) * 132] << 16);
        u32 w3 = (u32)tp[(g * 8 + 6) * 132] | ((u32)tp[(g * 8 + 7) * 132] << 16);
        uint4 bu; bu.x = w0; bu.y = w1; bu.z = w2; bu.w = w3;
        uacc[nt] = __builtin_amdgcn_mfma_f32_16x16x32_bf16(af, *(bf16x8*)&bu, uacc[nt], 0, 0, 0);
    }
    if (w < 2 && g < 2) {
#pragma unroll
        for (int nt = 0; nt < 8; nt++)
#pragma unroll
            for (int r = 0; r < 4; r++)
                vlds[w][(g * 4 + r) * 128 + nt * 16 + c16] = uacc[nt][r];
    }
    __syncthreads();
    if (w >= 2 && g < 2) {
#pragma unroll
        for (int nt = 0; nt < 8; nt++)
#pragma unroll
            for (int r = 0; r < 4; r++)
                vlds[w - 2][(g * 4 + r) * 128 + nt * 16 + c16] += uacc[nt][r];
    }
    __syncthreads();
    float* vout = vecp + ((size_t)blk << 10);
#pragma unroll
    for (int rep = 0; rep < 4; rep++) {
        int o = rep * 256 + t;
        vout[o] = vlds[0][o] + vlds[1][o];
    }
    if (t < 8) denp[blk * 8 + t] = dlds[0][t] + dlds[1][t] + dlds[2][t] + dlds[3][t];
}

// ---------- K5: 512-thread parallel update ----------

__device__ inline float sum512(float v, float* red8) {
#pragma unroll
    for (int o = 32; o; o >>= 1) v += __shfl_down(v, o);
    __syncthreads();
    if ((threadIdx.x & 63) == 0) red8[threadIdx.x >> 6] = v;
    __syncthreads();
    float s = 0.f;
#pragma unroll
    for (int i = 0; i < 8; i++) s += red8[i];
    return s;
}

__device__ inline float reduce4(float part, float* praw, int qq, int d) {
    __syncthreads();
    praw[qq * 128 + d] = part;
    __syncthreads();
    return praw[d] + praw[128 + d] + praw[256 + d] + praw[384 + d];
}

__global__ __launch_bounds__(512) void k5_update(
    const float* __restrict__ vecp, const float* __restrict__ denp,
    const float* __restrict__ wv, const float* __restrict__ bv,
    const float* __restrict__ wihT, const float* __restrict__ whhT,
    const float* __restrict__ bih, const float* __restrict__ bhh,
    const float* __restrict__ lnfg, const float* __restrict__ lnfb,
    const float* __restrict__ m1w, const float* __restrict__ m1b,
    const float* __restrict__ m2w, const float* __restrict__ m2b,
    float* __restrict__ slots,
    const float* __restrict__ lnsg, const float* __restrict__ lnsb,
    const float* __restrict__ wq, const float* __restrict__ bq,
    const float* __restrict__ wkT, const float* __restrict__ bk,
    float* __restrict__ qt, float* __restrict__ qc,
    float* __restrict__ out, int compute_q, int write_out) {
    __shared__ float sA[128], sB[128], sC[128], sH[128], sQ[128];
    __shared__ float praw[512];
    __shared__ float red8[8];
    __shared__ float gsc[6][512];
    int t = threadIdx.x;
    int bs = blockIdx.x;
    int b = bs >> 3, slot = bs & 7;
    int d = t & 127, qq = t >> 7;

    float dvp = (t < 256) ? denp[((size_t)(b * 256) + t) * 8 + slot] : 0.f;
    float dv = sum512(dvp, red8);

    float vs = 0.f;
    const float* vp0 = vecp + (((size_t)(b * 256 + qq * 64)) << 10) + slot * 128 + d;
#pragma unroll 8
    for (int s = 0; s < 64; s++) vs += vp0[(size_t)s << 10];
    float vtot = reduce4(vs, praw, qq, d);
    if (qq == 0) { sA[d] = vtot / dv; sC[d] = slots[bs * 128 + d]; }
    __syncthreads();

    float up = 0.f;
    {
        const float* wvp = wv + (size_t)(qq * 32) * 128 + d;
#pragma unroll 8
        for (int i = 0; i < 32; i++) up = fmaf(sA[qq * 32 + i], wvp[i * 128], up);
    }
    float updt = reduce4(up, praw, qq, d) + bv[d];
    if (qq == 0) sB[d] = updt;
    __syncthreads();

#pragma unroll 1
    for (int gx = 0; gx < 3; gx++) {
        int g = gx * 128 + d;
        float ap = 0.f, hp = 0.f;
        const float* wi = wihT + (size_t)(qq * 32) * 384 + g;
        const float* wh = whhT + (size_t)(qq * 32) * 384 + g;
#pragma unroll 8
        for (int i = 0; i < 32; i++) {
            ap = fmaf(sB[qq * 32 + i], wi[i * 384], ap);
            hp = fmaf(sC[qq * 32 + i], wh[i * 384], hp);
        }
        gsc[gx * 2][t] = ap;
        gsc[gx * 2 + 1][t] = hp;
    }
    __syncthreads();
    float gi0 = gsc[0][d] + gsc[0][128 + d] + gsc[0][256 + d] + gsc[0][384 + d] + bih[d];
    float gh0 = gsc[1][d] + gsc[1][128 + d] + gsc[1][256 + d] + gsc[1][384 + d] + bhh[d];
    float gi1 = gsc[2][d] + gsc[2][128 + d] + gsc[2][256 + d] + gsc[2][384 + d] + bih[128 + d];
    float gh1 = gsc[3][d] + gsc[3][128 + d] + gsc[3][256 + d] + gsc[3][384 + d] + bhh[128 + d];
    float gi2 = gsc[4][d] + gsc[4][128 + d] + gsc[4][256 + d] + gsc[4][384 + d] + bih[256 + d];
    float gh2 = gsc[5][d] + gsc[5][128 + d] + gsc[5][256 + d] + gsc[5][384 + d] + bhh[256 + d];
    float rg = 1.f / (1.f + expf(-(gi0 + gh0)));
    float zg = 1.f / (1.f + expf(-(gi1 + gh1)));
    float ng = tanhf(fmaf(rg, gh2, gi2));
    float hnew = (1.f - zg) * ng + zg * sC[d];
    __syncthreads();
    if (qq == 0) sH[d] = hnew;
    __syncthreads();

    float xh = (t < 128) ? sH[t] : 0.f;
    float mh = sum512(xh, red8) * (1.0f / 128.0f);
    float eh = xh - mh;
    float vh = sum512((t < 128) ? eh * eh : 0.f, red8) * (1.0f / 128.0f);
    float invh = rsqrtf(vh + 1e-5f);
    __syncthreads();
    if (t < 128) sA[t] = fmaf(eh * invh, lnfg[t], lnfb[t]);
    __syncthreads();

    float p1 = 0.f;
    {
        const float* m1p = m1w + (size_t)(qq * 32) * 128 + d;
#pragma unroll 8
        for (int i = 0; i < 32; i++) p1 = fmaf(sA[qq * 32 + i], m1p[i * 128], p1);
    }
    float m1v = reduce4(p1, praw, qq, d) + m1b[d];
    if (qq == 0) sB[d] = m1v;
    __syncthreads();

    float p2 = 0.f;
    {
        const float* m2p = m2w + (size_t)(qq * 32) * 128 + d;
#pragma unroll 8
        for (int i = 0; i < 32; i++) p2 = fmaf(sB[qq * 32 + i], m2p[i * 128], p2);
    }
    float m2v = reduce4(p2, praw, qq, d) + m2b[d];
    float snew = sH[d] + m2v;
    __syncthreads();
    if (qq == 0) {
        slots[bs * 128 + d] = snew;
        if (write_out) out[bs * 128 + d] = snew;
        sH[d] = snew;
    }
    __syncthreads();

    if (compute_q) {
        float xs = (t < 128) ? sH[t] : 0.f;
        float ms = sum512(xs, red8) * (1.0f / 128.0f);
        float es = xs - ms;
        float vs2 = sum512((t < 128) ? es * es : 0.f, red8) * (1.0f / 128.0f);
        float invs = rsqrtf(vs2 + 1e-5f);
        __syncthreads();
        if (t < 128) sA[t] = fmaf(es * invs, lnsg[t], lnsb[t]);
        __syncthreads();
        float pq = 0.f;
        {
            const float* wqp = wq + (size_t)(qq * 32) * 128 + d;
#pragma unroll 8
            for (int i = 0; i < 32; i++) pq = fmaf(sA[qq * 32 + i], wqp[i * 128], pq);
        }
        float qv = reduce4(pq, praw, qq, d) + bq[d];
        if (qq == 0) sQ[d] = qv;
        __syncthreads();
        float pa = 0.f;
        {
            const float* wkp = wkT + (size_t)(qq * 32) * 128 + d;
#pragma unroll 8
            for (int j = 0; j < 32; j++) pa = fmaf(wkp[j * 128], sQ[qq * 32 + j], pa);
        }
        const float scale = 0.08838834764831845f;
        float a2 = reduce4(pa, praw, qq, d) * scale;
        if (qq == 0) qt[bs * 128 + d] = a2;
        float xpr = (t < 128) ? sQ[t] * bk[t] : 0.f;
        float pr = sum512(xpr, red8);
        if (t == 0) qc[bs] = pr * scale;
    }
}

// ---------- launch ----------

extern "C" void kernel_launch(void* const* d_in, const int* in_sizes, int n_in,
                              void* d_out, int out_size, void* d_ws, size_t ws_size,
                              hipStream_t stream) {
    const float* inputs = (const float*)d_in[0];
    const float* embed  = (const float*)d_in[1];
    const float* mu     = (const float*)d_in[2];
    const float* sg     = (const float*)d_in[3];
    const float* w0 = (const float*)d_in[4];  const float* b0 = (const float*)d_in[5];
    const float* w1 = (const float*)d_in[6];  const float* b1 = (const float*)d_in[7];
    const float* w2 = (const float*)d_in[8];  const float* b2 = (const float*)d_in[9];
    const float* w3 = (const float*)d_in[10]; const float* b3 = (const float*)d_in[11];
    const float* w4 = (const float*)d_in[12]; const float* b4 = (const float*)d_in[13];
    const float* w5 = (const float*)d_in[14]; const float* b5 = (const float*)d_in[15];
    const float* w7 = (const float*)d_in[16]; const float* b7 = (const float*)d_in[17];
    const float* wq = (const float*)d_in[18]; const float* bq = (const float*)d_in[19];
    const float* wk = (const float*)d_in[20]; const float* bk = (const float*)d_in[21];
    const float* wv = (const float*)d_in[22]; const float* bv = (const float*)d_in[23];
    const float* ln_in_g = (const float*)d_in[24]; const float* ln_in_b = (const float*)d_in[25];
    const float* ln_sl_g = (const float*)d_in[26]; const float* ln_sl_b = (const float*)d_in[27];
    const float* ln_ff_g = (const float*)d_in[28]; const float* ln_ff_b = (const float*)d_in[29];
    const float* gwih = (const float*)d_in[30]; const float* gwhh = (const float*)d_in[31];
    const float* gbih = (const float*)d_in[32]; const float* gbhh = (const float*)d_in[33];
    const float* m1w = (const float*)d_in[34]; const float* m1b = (const float*)d_in[35];
    const float* m2w = (const float*)d_in[36]; const float* m2b = (const float*)d_in[37];

    char* ws = (char*)d_ws;
    u16* hlnb = (u16*)ws;
    size_t off = (size_t)NB_ * 128 * 2;  // 64 MB bf16 hln row-major
    float* Wh    = (float*)(ws + off); off += 66 * 128 * 4;
    float* bh    = (float*)(ws + off); off += 128 * 4;
    float* slots = (float*)(ws + off); off += 64 * 128 * 4;
    float* qt    = (float*)(ws + off); off += 64 * 128 * 4;
    float* qc    = (float*)(ws + off); off += 64 * 4;
    float* vecp  = (float*)(ws + off); off += (size_t)2048 * 1024 * 4;  // 8 MB
    float* denp  = (float*)(ws + off); off += 2048 * 8 * 4;
    float* wihT  = (float*)(ws + off); off += 384 * 128 * 4;
    float* whhT  = (float*)(ws + off); off += 384 * 128 * 4;
    float* wkT   = (float*)(ws + off); off += 128 * 128 * 4;
    u16* whiT    = (u16*)(ws + off); off += 128 * 96 * 2;

    k0_transpose<<<448, 256, 0, stream>>>(gwih, gwhh, wk, wihT, whhT, wkT);
    k1_setup<<<1, 256, 0, stream>>>(w0, b0, w1, b1, w2, b2, w3, b3, w4, b4, w5, b5,
                                    w7, b7, mu, sg, Wh, bh, slots, whiT);
    k2_hln<<<NB_ / 128, 256, 0, stream>>>(inputs, embed, whiT, bh,
                                          ln_in_g, ln_in_b, hlnb);
    k3_q<<<64, 128, 0, stream>>>(slots, ln_sl_g, ln_sl_b, wq, bq, wkT, bk, qt, qc);
    for (int it = 0; it < 3; it++) {
        k4_attn<<<2048, 256, 0, stream>>>((const uint4*)hlnb, qt, qc, vecp, denp);
        k5_update<<<64, 512, 0, stream>>>(vecp, denp, wv, bv, wihT, whhT, gbih, gbhh,
                                          ln_ff_g, ln_ff_b, m1w, m1b, m2w, m2b, slots,
                                          ln_sl_g, ln_sl_b, wq, bq, wkT, bk, qt, qc,
                                          (float*)d_out, (it < 2) ? 1 : 0, (it == 2) ? 1 : 0);
    }
}

// Round 18
// 261.928 us; speedup vs baseline: 1.8514x; 1.0458x over previous
//
#include <hip/hip_runtime.h>

// SlotAttention fused implementation (bf16 hln, single layout, MFMA).
//   - 6-layer linear stack folded into effective 66->128 affine (Wh, bh).
//   - k,v folded out of N:  q.k_n = (wk@q).hln_n + q.bk ;
//     updates = (sum attn*hln)/den @ wv + bv
//   - hln bf16 row-major [NB][128] only (64 MB, L3-resident).
//   - slot init: JAX partitionable threefry: bits[i] = o0^o1, counter (0,i).
//   - k2: single-bf16 MFMA GEMM; E pre-converted bf16 in LDS.
//   - k4: 1024 blocks x 4 waves x 2 pipelined 32-row tiles; transposed
//     per-wave tile (b64 B-frag reads); vlds aliased into tiles.
//   - k5: 512 threads; GEMVs as 32-iter partials + LDS tree reduce.

#define B_  8
#define N_  32768
#define NB_ (B_ * N_)   // 262144 rows
#define D_  128
#define S_  8

typedef unsigned int u32;
typedef unsigned short u16;
typedef __attribute__((ext_vector_type(8))) short bf16x8;
typedef __attribute__((ext_vector_type(4))) float f32x4;

__device__ inline u32 bfr1(float x) {  // f32 -> bf16 (RNE)
    u32 u = __float_as_uint(x);
    return (u + 0x7FFFu + ((u >> 16) & 1u)) >> 16;
}
__device__ inline u32 bfpack2(u32 lo, u32 hi) { return lo | (hi << 16); }

// threefry2x32, key = (0, 42)
__device__ inline void threefry42(u32 c0, u32 c1, u32& o0, u32& o1) {
    const u32 k0 = 0u, k1 = 42u, k2 = 0x1BD11BDAu ^ 0u ^ 42u;
    const u32 ks[3] = {k0, k1, k2};
    u32 x0 = c0 + k0, x1 = c1 + k1;
    const int rA[4] = {13, 15, 26, 6}, rB[4] = {17, 29, 16, 24};
#pragma unroll
    for (int i = 0; i < 5; i++) {
#pragma unroll
        for (int k = 0; k < 4; k++) {
            int r = (i & 1) ? rB[k] : rA[k];
            x0 += x1;
            x1 = (x1 << r) | (x1 >> (32 - r));
            x1 ^= x0;
        }
        x0 += ks[(i + 1) % 3];
        x1 += ks[(i + 2) % 3] + (u32)(i + 1);
    }
    o0 = x0; o1 = x1;
}

// jax uniform(-0.99999994, 1) -> sqrt(2)*erfinv
__device__ inline float bits_to_normal(u32 b) {
    float f = __uint_as_float((b >> 9) | 0x3f800000u) - 1.0f;
    const float lo = -0.99999994f;
    float r = fmaxf(lo, f * 1.99999994f + lo);
    float w = -log1pf(-r * r);
    float p;
    if (w < 5.0f) {
        w -= 2.5f;
        p = 2.81022636e-08f;
        p = fmaf(p, w, 3.43273939e-07f);
        p = fmaf(p, w, -3.5233877e-06f);
        p = fmaf(p, w, -4.39150654e-06f);
        p = fmaf(p, w, 0.00021858087f);
        p = fmaf(p, w, -0.00125372503f);
        p = fmaf(p, w, -0.00417768164f);
        p = fmaf(p, w, 0.246640727f);
        p = fmaf(p, w, 1.50140941f);
    } else {
        w = sqrtf(w) - 3.0f;
        p = -0.000200214257f;
        p = fmaf(p, w, 0.000100950558f);
        p = fmaf(p, w, 0.00134934322f);
        p = fmaf(p, w, -0.00367342844f);
        p = fmaf(p, w, 0.00573950773f);
        p = fmaf(p, w, -0.0076224613f);
        p = fmaf(p, w, 0.00943887047f);
        p = fmaf(p, w, 1.00167406f);
        p = fmaf(p, w, 2.83297682f);
    }
    return 1.41421356f * (p * r);
}

// 128-thread block sum (k3 only)
__device__ inline float block128_sum(float v, float* red) {
#pragma unroll
    for (int o = 32; o; o >>= 1) v += __shfl_down(v, o);
    __syncthreads();
    if ((threadIdx.x & 63) == 0) red[threadIdx.x >> 6] = v;
    __syncthreads();
    return red[0] + red[1];
}

// emit_q for 128-thread k3
__device__ void emit_q(float x, int bs,
                       const float* lnsg, const float* lnsb,
                       const float* wq, const float* bq,
                       const float* wkT, const float* bk,
                       float* qt, float* qc,
                       float* shA, float* red) {
    int t = threadIdx.x;
    float m = block128_sum(x, red) * (1.0f / 128.0f);
    float e = x - m;
    float var = block128_sum(e * e, red) * (1.0f / 128.0f);
    float inv = rsqrtf(var + 1e-5f);
    __syncthreads();
    shA[t] = fmaf(e * inv, lnsg[t], lnsb[t]);
    __syncthreads();
    float q = bq[t];
#pragma unroll 4
    for (int i = 0; i < 128; i++) q = fmaf(shA[i], wq[i * 128 + t], q);
    __syncthreads();
    shA[t] = q;
    __syncthreads();
    float a2 = 0.f;
#pragma unroll 4
    for (int j = 0; j < 128; j++) a2 = fmaf(wkT[j * 128 + t], shA[j], a2);
    const float scale = 0.08838834764831845f;  // 128^-0.5
    qt[bs * 128 + t] = a2 * scale;
    float pr = block128_sum(shA[t] * bk[t], red);
    if (t == 0) qc[bs] = pr * scale;
}

// ---------- K0: transpose gru weights + wk ----------

__global__ __launch_bounds__(256) void k0_transpose(
    const float* __restrict__ wih, const float* __restrict__ whh,
    const float* __restrict__ wk,
    float* __restrict__ wihT, float* __restrict__ whhT, float* __restrict__ wkT) {
    int idx = blockIdx.x * 256 + threadIdx.x;
    if (idx < 49152) {
        int d = idx / 384, g = idx % 384;
        wihT[idx] = wih[g * 128 + d];
    } else if (idx < 98304) {
        int o = idx - 49152;
        int d = o / 384, g = o % 384;
        whhT[o] = whh[g * 128 + d];
    } else if (idx < 114688) {
        int o = idx - 98304;
        int j = o >> 7, tcol = o & 127;
        wkT[o] = wk[tcol * 128 + j];
    }
}

// ---------- K1: fold weights, init slots, bf16 W ----------

__global__ __launch_bounds__(256) void k1_setup(
    const float* __restrict__ w0, const float* __restrict__ b0,
    const float* __restrict__ w1, const float* __restrict__ b1,
    const float* __restrict__ w2, const float* __restrict__ b2,
    const float* __restrict__ w3, const float* __restrict__ b3,
    const float* __restrict__ w4, const float* __restrict__ b4,
    const float* __restrict__ w5, const float* __restrict__ b5,
    const float* __restrict__ w7, const float* __restrict__ b7,
    const float* __restrict__ mu, const float* __restrict__ sg,
    float* __restrict__ Wh, float* __restrict__ bh, float* __restrict__ slots,
    u16* __restrict__ whiT) {
    __shared__ float A[192], Bt[96], bb[64], bb2[32];
    __shared__ float stats[2];
    int t = threadIdx.x;
    for (int i = t; i < 192; i += 256) A[i] = w0[i];
    for (int i = t; i < 64; i += 256) bb[i] = b0[i];
    __syncthreads();
    const float* wl[5] = {w1, w2, w3, w4, w5};
    const float* bl[5] = {b1, b2, b3, b4, b5};
    int kin = 64;
    for (int l = 0; l < 5; l++) {
        const float* w = wl[l];
        const float* bias = bl[l];
        if (t < 96) {
            int i = t / 32, j = t % 32;
            float acc = 0.f;
            for (int k = 0; k < kin; k++) acc += A[i * kin + k] * w[k * 32 + j];
            Bt[i * 32 + j] = acc;
        } else if (t < 128) {
            int j = t - 96;
            float acc = bias[j];
            for (int k = 0; k < kin; k++) acc += bb[k] * w[k * 32 + j];
            bb2[j] = acc;
        }
        __syncthreads();
        if (t < 96) A[t] = Bt[t];
        if (t < 32) bb[t] = bb2[t];
        __syncthreads();
        kin = 32;
    }
    for (int idx = t; idx < 66 * 128; idx += 256) {
        int i = idx >> 7, j = idx & 127;
        float acc = w7[idx];
        if (i < 3) {
            for (int k = 0; k < 32; k++) acc += A[i * 32 + k] * w7[(66 + k) * 128 + j];
        }
        Wh[idx] = acc;
    }
    for (int j = t; j < 128; j += 256) {
        float acc = b7[j];
        for (int k = 0; k < 32; k++) acc += bb[k] * w7[(66 + k) * 128 + j];
        bh[j] = acc;
    }
    if (t == 0) {
        float s1 = 0.f, s2 = 0.f;
        for (int d = 0; d < 128; d++) { s1 += mu[d]; s2 += sg[d]; }
        float mmu = s1 / 128.f, msg = s2 / 128.f;
        float ss = 0.f;
        for (int d = 0; d < 128; d++) { float e = sg[d] - msg; ss += e * e; }
        stats[0] = mmu;
        stats[1] = sqrtf(64.f * ss / 8191.f);
    }
    __syncthreads();
    for (int idx = t; idx < 128 * 96; idx += 256) {
        int col = idx / 96, k = idx - col * 96;
        float v = (k < 66) ? Wh[k * 128 + col] : 0.f;
        whiT[idx] = (u16)bfr1(v);
    }
    float mean = stats[0], sd = stats[1];
    for (int p = t; p < 8192; p += 256) {
        u32 o0, o1;
        threefry42(0u, (u32)p, o0, o1);
        slots[p] = fmaf(sd, bits_to_normal(o0 ^ o1), mean);
    }
}

// ---------- K2: single-bf16 MFMA build of hln ----------

__global__ __launch_bounds__(256) void k2_hln(
    const float* __restrict__ inputs, const float* __restrict__ embed,
    const u16* __restrict__ whiT, const float* __restrict__ bh,
    const float* __restrict__ g, const float* __restrict__ bbias,
    u16* __restrict__ hlnb) {
    __shared__ __align__(16) char smem[34816];  // ebuf u16[128][104] / T u16[128][136]
    __shared__ float bhl[128], gl[128], bl[128];
    int t = threadIdx.x;
    u16* ebuf = (u16*)smem;
    size_t rbase = (size_t)blockIdx.x * 128;
    for (int idx = t; idx < 384; idx += 256)
        ebuf[(idx / 3) * 104 + (idx % 3)] = (u16)bfr1(inputs[rbase * 3 + idx]);
    for (int idx = t; idx < 128 * 63; idx += 256) {
        int r = idx / 63, i = idx - r * 63;
        ebuf[r * 104 + 3 + i] = (u16)bfr1(embed[rbase * 63 + idx]);
    }
    for (int idx = t; idx < 128 * 30; idx += 256) {
        int r = idx / 30, i = idx - r * 30;
        ebuf[r * 104 + 66 + i] = 0;
    }
    if (t < 128) { bhl[t] = bh[t]; gl[t] = g[t]; bl[t] = bbias[t]; }
    __syncthreads();

    int w = t >> 6, l = t & 63;
    int c16 = l & 15, g4 = l >> 4;
    int wr0 = w * 32;
    float bhc[8], gc[8], bc[8];
#pragma unroll
    for (int nt = 0; nt < 8; nt++) {
        bhc[nt] = bhl[nt * 16 + c16];
        gc[nt] = gl[nt * 16 + c16];
        bc[nt] = bl[nt * 16 + c16];
    }
    f32x4 acc[2][8];
#pragma unroll
    for (int mi = 0; mi < 2; mi++)
#pragma unroll
        for (int nt = 0; nt < 8; nt++)
            acc[mi][nt] = (f32x4){bhc[nt], bhc[nt], bhc[nt], bhc[nt]};

#pragma unroll
    for (int kc = 0; kc < 3; kc++) {
        bf16x8 a0 = *(const bf16x8*)&ebuf[(wr0 + c16) * 104 + kc * 32 + g4 * 8];
        bf16x8 a1 = *(const bf16x8*)&ebuf[(wr0 + 16 + c16) * 104 + kc * 32 + g4 * 8];
#pragma unroll
        for (int nt = 0; nt < 8; nt++) {
            uint4 bw = *(const uint4*)(whiT + (size_t)(nt * 16 + c16) * 96 + kc * 32 + g4 * 8);
            bf16x8 bf = *(bf16x8*)&bw;
            acc[0][nt] = __builtin_amdgcn_mfma_f32_16x16x32_bf16(a0, bf, acc[0][nt], 0, 0, 0);
            acc[1][nt] = __builtin_amdgcn_mfma_f32_16x16x32_bf16(a1, bf, acc[1][nt], 0, 0, 0);
        }
    }

    __syncthreads();
    u16* T = (u16*)smem;           // [128][136]
#pragma unroll
    for (int mi = 0; mi < 2; mi++) {
#pragma unroll
        for (int i = 0; i < 4; i++) {
            float s = 0.f;
#pragma unroll
            for (int nt = 0; nt < 8; nt++) s += acc[mi][nt][i];
            s += __shfl_xor(s, 1); s += __shfl_xor(s, 2);
            s += __shfl_xor(s, 4); s += __shfl_xor(s, 8);
            float m = s * (1.0f / 128.0f);
            float v = 0.f;
#pragma unroll
            for (int nt = 0; nt < 8; nt++) { float d = acc[mi][nt][i] - m; v = fmaf(d, d, v); }
            v += __shfl_xor(v, 1); v += __shfl_xor(v, 2);
            v += __shfl_xor(v, 4); v += __shfl_xor(v, 8);
            float inv = rsqrtf(v * (1.0f / 128.0f) + 1e-5f);
            int row = wr0 + mi * 16 + g4 * 4 + i;
#pragma unroll
            for (int nt = 0; nt < 8; nt++) {
                float val = fmaf((acc[mi][nt][i] - m) * inv, gc[nt], bc[nt]);
                T[row * 136 + nt * 16 + c16] = (u16)bfr1(val);
            }
        }
    }
    __syncthreads();
    {
        int r = t >> 1, hf = t & 1;
        const u16* Tr = T + r * 136 + hf * 64;
        u16* dst = hlnb + (rbase + r) * 128 + hf * 64;
#pragma unroll
        for (int j = 0; j < 8; j++) {
            uint4 v = *(const uint4*)(Tr + j * 8);
            *(uint4*)(dst + j * 8) = v;
        }
    }
}

// ---------- K3: initial q from slots ----------

__global__ __launch_bounds__(128) void k3_q(
    const float* __restrict__ slots,
    const float* __restrict__ lnsg, const float* __restrict__ lnsb,
    const float* __restrict__ wq, const float* __restrict__ bq,
    const float* __restrict__ wkT, const float* __restrict__ bk,
    float* __restrict__ qt, float* __restrict__ qc) {
    __shared__ float shA[128];
    __shared__ float red[2];
    int bs = blockIdx.x;
    float x = slots[bs * 128 + threadIdx.x];
    emit_q(x, bs, lnsg, lnsb, wq, bq, wkT, bk, qt, qc, shA, red);
}

// ---------- K4: MFMA attention, 2 pipelined tiles/wave, transposed tile ----------
// 1024 blocks x 4 waves; wave does rows [slab*256 + w*32, +32) and +128.
// tileT[dim][36] u16 per wave; B-frags = 2 x ds_read_b64 per nt.

__global__ __launch_bounds__(256) void k4_attn(
    const uint4* __restrict__ hlnb4,
    const float* __restrict__ qt, const float* __restrict__ qc,
    float* __restrict__ vecp, float* __restrict__ denp) {
    __shared__ __align__(16) u16 tiles[4][128 * 36];   // 36864 B (vlds aliased here)
    __shared__ __align__(16) u16 attnP[4][16 * 40];    // 5120 B
    __shared__ float dlds[4][8];
    int t = threadIdx.x;
    int w = t >> 6, l = t & 63;
    int blk = blockIdx.x;
    int b = blk >> 7, slab = blk & 127;
    size_t row0 = (size_t)b * N_ + (size_t)slab * 256 + (size_t)w * 32;
    int c16 = l & 15, g = l >> 4;
    u16* tw = tiles[w];

    // q B-frags (slot = c16, zero for c16>=8)
    bf16x8 qf[4];
#pragma unroll
    for (int kc = 0; kc < 4; kc++) {
        uint4 qu = {0u, 0u, 0u, 0u};
        if (c16 < 8) {
            const float* qp = qt + b * 1024 + c16 * 128 + kc * 32 + g * 8;
            float4 qa = *(const float4*)qp;
            float4 qb = *(const float4*)(qp + 4);
            qu.x = bfpack2(bfr1(qa.x), bfr1(qa.y));
            qu.y = bfpack2(bfr1(qa.z), bfr1(qa.w));
            qu.z = bfpack2(bfr1(qb.x), bfr1(qb.y));
            qu.w = bfpack2(bfr1(qb.z), bfr1(qb.w));
        }
        qf[kc] = *(bf16x8*)&qu;
    }
    float qcv = (c16 < 8) ? qc[b * 8 + c16] : 0.f;

    f32x4 uacc[8];
#pragma unroll
    for (int nt = 0; nt < 8; nt++) uacc[nt] = (f32x4){0.f, 0.f, 0.f, 0.f};
    float denacc = 0.f;

    uint4 st[8];   // current tile's 2x4 row-chunks (mt in 0..1, kc in 0..3)
#pragma unroll
    for (int mt = 0; mt < 2; mt++)
#pragma unroll
        for (int kc = 0; kc < 4; kc++)
            st[mt * 4 + kc] = hlnb4[(row0 + mt * 16 + c16) * 16 + kc * 4 + g];

    for (int tt = 0; tt < 2; tt++) {
        // ---- phase 1: 8 MFMA + transposed tile store ----
        f32x4 dacc[2];
        dacc[0] = (f32x4){0.f, 0.f, 0.f, 0.f};
        dacc[1] = (f32x4){0.f, 0.f, 0.f, 0.f};
#pragma unroll
        for (int mt = 0; mt < 2; mt++) {
#pragma unroll
            for (int kc = 0; kc < 4; kc++) {
                uint4 au = st[mt * 4 + kc];
                dacc[mt] = __builtin_amdgcn_mfma_f32_16x16x32_bf16(*(bf16x8*)&au, qf[kc], dacc[mt], 0, 0, 0);
                int r = mt * 16 + c16;
                int d0 = kc * 32 + g * 8;
                tw[(d0 + 0) * 36 + r] = (u16)(au.x & 0xFFFF);
                tw[(d0 + 1) * 36 + r] = (u16)(au.x >> 16);
                tw[(d0 + 2) * 36 + r] = (u16)(au.y & 0xFFFF);
                tw[(d0 + 3) * 36 + r] = (u16)(au.y >> 16);
                tw[(d0 + 4) * 36 + r] = (u16)(au.z & 0xFFFF);
                tw[(d0 + 5) * 36 + r] = (u16)(au.z >> 16);
                tw[(d0 + 6) * 36 + r] = (u16)(au.w & 0xFFFF);
                tw[(d0 + 7) * 36 + r] = (u16)(au.w >> 16);
            }
        }
        // prefetch next tile while softmax/phase2 run
        if (tt == 0) {
            size_t rowB = row0 + 128;
#pragma unroll
            for (int mt = 0; mt < 2; mt++)
#pragma unroll
                for (int kc = 0; kc < 4; kc++)
                    st[mt * 4 + kc] = hlnb4[(rowB + mt * 16 + c16) * 16 + kc * 4 + g];
        }
        // ---- softmax over slots (c16 lanes, masks 1/2/4) ----
#pragma unroll
        for (int mt = 0; mt < 2; mt++) {
            float pv[4];
#pragma unroll
            for (int r = 0; r < 4; r++) {
                float v = dacc[mt][r] + qcv;
                float mx = v;
                mx = fmaxf(mx, __shfl_xor(mx, 1));
                mx = fmaxf(mx, __shfl_xor(mx, 2));
                mx = fmaxf(mx, __shfl_xor(mx, 4));
                float e = __expf(v - mx);
                float ssum = e;
                ssum += __shfl_xor(ssum, 1);
                ssum += __shfl_xor(ssum, 2);
                ssum += __shfl_xor(ssum, 4);
                float a = (c16 < 8) ? fmaf(e, 1.0f / ssum, 1e-8f) : 0.f;
                pv[r] = a;
                denacc += a;
            }
            uint2 pw;
            pw.x = bfpack2(bfr1(pv[0]), bfr1(pv[1]));
            pw.y = bfpack2(bfr1(pv[2]), bfr1(pv[3]));
            *(uint2*)&attnP[w][c16 * 40 + mt * 16 + g * 4] = pw;
        }
        // ---- phase 2: U += P^T[16x32] . H[32x128], 8 MFMA ----
        uint4 afu = *(const uint4*)&attnP[w][c16 * 40 + g * 8];
        bf16x8 af = *(bf16x8*)&afu;
#pragma unroll
        for (int nt = 0; nt < 8; nt++) {
            const u16* tp = tw + (nt * 16 + c16) * 36 + g * 8;
            uint2 blo = *(const uint2*)tp;
            uint2 bhi = *(const uint2*)(tp + 4);
            uint4 bu; bu.x = blo.x; bu.y = blo.y; bu.z = bhi.x; bu.w = bhi.y;
            uacc[nt] = __builtin_amdgcn_mfma_f32_16x16x32_bf16(af, *(bf16x8*)&bu, uacc[nt], 0, 0, 0);
        }
    }
    denacc += __shfl_xor(denacc, 16);
    denacc += __shfl_xor(denacc, 32);
    if (l < 8) dlds[w][l] = denacc;

    // ---- cross-wave reduce (vlds aliased into tiles region) ----
    __syncthreads();
    float* vlds0 = (float*)&tiles[0][0];
    float* vlds1 = vlds0 + 1024;
    if (w < 2 && g < 2) {
        float* vb = (w == 0) ? vlds0 : vlds1;
#pragma unroll
        for (int nt = 0; nt < 8; nt++)
#pragma unroll
            for (int r = 0; r < 4; r++)
                vb[(g * 4 + r) * 128 + nt * 16 + c16] = uacc[nt][r];
    }
    __syncthreads();
    if (w >= 2 && g < 2) {
        float* vb = (w == 2) ? vlds0 : vlds1;
#pragma unroll
        for (int nt = 0; nt < 8; nt++)
#pragma unroll
            for (int r = 0; r < 4; r++)
                vb[(g * 4 + r) * 128 + nt * 16 + c16] += uacc[nt][r];
    }
    __syncthreads();
    float* vout = vecp + ((size_t)blk << 10);
#pragma unroll
    for (int rep = 0; rep < 4; rep++) {
        int o = rep * 256 + t;
        vout[o] = vlds0[o] + vlds1[o];
    }
    if (t < 8) denp[blk * 8 + t] = dlds[0][t] + dlds[1][t] + dlds[2][t] + dlds[3][t];
}

// ---------- K5: 512-thread parallel update ----------

__device__ inline float sum512(float v, float* red8) {
#pragma unroll
    for (int o = 32; o; o >>= 1) v += __shfl_down(v, o);
    __syncthreads();
    if ((threadIdx.x & 63) == 0) red8[threadIdx.x >> 6] = v;
    __syncthreads();
    float s = 0.f;
#pragma unroll
    for (int i = 0; i < 8; i++) s += red8[i];
    return s;
}

__device__ inline float reduce4(float part, float* praw, int qq, int d) {
    __syncthreads();
    praw[qq * 128 + d] = part;
    __syncthreads();
    return praw[d] + praw[128 + d] + praw[256 + d] + praw[384 + d];
}

__global__ __launch_bounds__(512) void k5_update(
    const float* __restrict__ vecp, const float* __restrict__ denp,
    const float* __restrict__ wv, const float* __restrict__ bv,
    const float* __restrict__ wihT, const float* __restrict__ whhT,
    const float* __restrict__ bih, const float* __restrict__ bhh,
    const float* __restrict__ lnfg, const float* __restrict__ lnfb,
    const float* __restrict__ m1w, const float* __restrict__ m1b,
    const float* __restrict__ m2w, const float* __restrict__ m2b,
    float* __restrict__ slots,
    const float* __restrict__ lnsg, const float* __restrict__ lnsb,
    const float* __restrict__ wq, const float* __restrict__ bq,
    const float* __restrict__ wkT, const float* __restrict__ bk,
    float* __restrict__ qt, float* __restrict__ qc,
    float* __restrict__ out, int compute_q, int write_out) {
    __shared__ float sA[128], sB[128], sC[128], sH[128], sQ[128];
    __shared__ float praw[512];
    __shared__ float red8[8];
    __shared__ float gsc[6][512];
    int t = threadIdx.x;
    int bs = blockIdx.x;
    int b = bs >> 3, slot = bs & 7;
    int d = t & 127, qq = t >> 7;

    float dvp = (t < 128) ? denp[((size_t)(b * 128) + t) * 8 + slot] : 0.f;
    float dv = sum512(dvp, red8);

    float vs = 0.f;
    const float* vp0 = vecp + (((size_t)(b * 128 + qq * 32)) << 10) + slot * 128 + d;
#pragma unroll 8
    for (int s = 0; s < 32; s++) vs += vp0[(size_t)s << 10];
    float vtot = reduce4(vs, praw, qq, d);
    if (qq == 0) { sA[d] = vtot / dv; sC[d] = slots[bs * 128 + d]; }
    __syncthreads();

    float up = 0.f;
    {
        const float* wvp = wv + (size_t)(qq * 32) * 128 + d;
#pragma unroll 8
        for (int i = 0; i < 32; i++) up = fmaf(sA[qq * 32 + i], wvp[i * 128], up);
    }
    float updt = reduce4(up, praw, qq, d) + bv[d];
    if (qq == 0) sB[d] = updt;
    __syncthreads();

#pragma unroll 1
    for (int gx = 0; gx < 3; gx++) {
        int g = gx * 128 + d;
        float ap = 0.f, hp = 0.f;
        const float* wi = wihT + (size_t)(qq * 32) * 384 + g;
        const float* wh = whhT + (size_t)(qq * 32) * 384 + g;
#pragma unroll 8
        for (int i = 0; i < 32; i++) {
            ap = fmaf(sB[qq * 32 + i], wi[i * 384], ap);
            hp = fmaf(sC[qq * 32 + i], wh[i * 384], hp);
        }
        gsc[gx * 2][t] = ap;
        gsc[gx * 2 + 1][t] = hp;
    }
    __syncthreads();
    float gi0 = gsc[0][d] + gsc[0][128 + d] + gsc[0][256 + d] + gsc[0][384 + d] + bih[d];
    float gh0 = gsc[1][d] + gsc[1][128 + d] + gsc[1][256 + d] + gsc[1][384 + d] + bhh[d];
    float gi1 = gsc[2][d] + gsc[2][128 + d] + gsc[2][256 + d] + gsc[2][384 + d] + bih[128 + d];
    float gh1 = gsc[3][d] + gsc[3][128 + d] + gsc[3][256 + d] + gsc[3][384 + d] + bhh[128 + d];
    float gi2 = gsc[4][d] + gsc[4][128 + d] + gsc[4][256 + d] + gsc[4][384 + d] + bih[256 + d];
    float gh2 = gsc[5][d] + gsc[5][128 + d] + gsc[5][256 + d] + gsc[5][384 + d] + bhh[256 + d];
    float rg = 1.f / (1.f + expf(-(gi0 + gh0)));
    float zg = 1.f / (1.f + expf(-(gi1 + gh1)));
    float ng = tanhf(fmaf(rg, gh2, gi2));
    float hnew = (1.f - zg) * ng + zg * sC[d];
    __syncthreads();
    if (qq == 0) sH[d] = hnew;
    __syncthreads();

    float xh = (t < 128) ? sH[t] : 0.f;
    float mh = sum512(xh, red8) * (1.0f / 128.0f);
    float eh = xh - mh;
    float vh = sum512((t < 128) ? eh * eh : 0.f, red8) * (1.0f / 128.0f);
    float invh = rsqrtf(vh + 1e-5f);
    __syncthreads();
    if (t < 128) sA[t] = fmaf(eh * invh, lnfg[t], lnfb[t]);
    __syncthreads();

    float p1 = 0.f;
    {
        const float* m1p = m1w + (size_t)(qq * 32) * 128 + d;
#pragma unroll 8
        for (int i = 0; i < 32; i++) p1 = fmaf(sA[qq * 32 + i], m1p[i * 128], p1);
    }
    float m1v = reduce4(p1, praw, qq, d) + m1b[d];
    if (qq == 0) sB[d] = m1v;
    __syncthreads();

    float p2 = 0.f;
    {
        const float* m2p = m2w + (size_t)(qq * 32) * 128 + d;
#pragma unroll 8
        for (int i = 0; i < 32; i++) p2 = fmaf(sB[qq * 32 + i], m2p[i * 128], p2);
    }
    float m2v = reduce4(p2, praw, qq, d) + m2b[d];
    float snew = sH[d] + m2v;
    __syncthreads();
    if (qq == 0) {
        slots[bs * 128 + d] = snew;
        if (write_out) out[bs * 128 + d] = snew;
        sH[d] = snew;
    }
    __syncthreads();

    if (compute_q) {
        float xs = (t < 128) ? sH[t] : 0.f;
        float ms = sum512(xs, red8) * (1.0f / 128.0f);
        float es = xs - ms;
        float vs2 = sum512((t < 128) ? es * es : 0.f, red8) * (1.0f / 128.0f);
        float invs = rsqrtf(vs2 + 1e-5f);
        __syncthreads();
        if (t < 128) sA[t] = fmaf(es * invs, lnsg[t], lnsb[t]);
        __syncthreads();
        float pq = 0.f;
        {
            const float* wqp = wq + (size_t)(qq * 32) * 128 + d;
#pragma unroll 8
            for (int i = 0; i < 32; i++) pq = fmaf(sA[qq * 32 + i], wqp[i * 128], pq);
        }
        float qv = reduce4(pq, praw, qq, d) + bq[d];
        if (qq == 0) sQ[d] = qv;
        __syncthreads();
        float pa = 0.f;
        {
            const float* wkp = wkT + (size_t)(qq * 32) * 128 + d;
#pragma unroll 8
            for (int j = 0; j < 32; j++) pa = fmaf(wkp[j * 128], sQ[qq * 32 + j], pa);
        }
        const float scale = 0.08838834764831845f;
        float a2 = reduce4(pa, praw, qq, d) * scale;
        if (qq == 0) qt[bs * 128 + d] = a2;
        float xpr = (t < 128) ? sQ[t] * bk[t] : 0.f;
        float pr = sum512(xpr, red8);
        if (t == 0) qc[bs] = pr * scale;
    }
}

// ---------- launch ----------

extern "C" void kernel_launch(void* const* d_in, const int* in_sizes, int n_in,
                              void* d_out, int out_size, void* d_ws, size_t ws_size,
                              hipStream_t stream) {
    const float* inputs = (const float*)d_in[0];
    const float* embed  = (const float*)d_in[1];
    const float* mu     = (const float*)d_in[2];
    const float* sg     = (const float*)d_in[3];
    const float* w0 = (const float*)d_in[4];  const float* b0 = (const float*)d_in[5];
    const float* w1 = (const float*)d_in[6];  const float* b1 = (const float*)d_in[7];
    const float* w2 = (const float*)d_in[8];  const float* b2 = (const float*)d_in[9];
    const float* w3 = (const float*)d_in[10]; const float* b3 = (const float*)d_in[11];
    const float* w4 = (const float*)d_in[12]; const float* b4 = (const float*)d_in[13];
    const float* w5 = (const float*)d_in[14]; const float* b5 = (const float*)d_in[15];
    const float* w7 = (const float*)d_in[16]; const float* b7 = (const float*)d_in[17];
    const float* wq = (const float*)d_in[18]; const float* bq = (const float*)d_in[19];
    const float* wk = (const float*)d_in[20]; const float* bk = (const float*)d_in[21];
    const float* wv = (const float*)d_in[22]; const float* bv = (const float*)d_in[23];
    const float* ln_in_g = (const float*)d_in[24]; const float* ln_in_b = (const float*)d_in[25];
    const float* ln_sl_g = (const float*)d_in[26]; const float* ln_sl_b = (const float*)d_in[27];
    const float* ln_ff_g = (const float*)d_in[28]; const float* ln_ff_b = (const float*)d_in[29];
    const float* gwih = (const float*)d_in[30]; const float* gwhh = (const float*)d_in[31];
    const float* gbih = (const float*)d_in[32]; const float* gbhh = (const float*)d_in[33];
    const float* m1w = (const float*)d_in[34]; const float* m1b = (const float*)d_in[35];
    const float* m2w = (const float*)d_in[36]; const float* m2b = (const float*)d_in[37];

    char* ws = (char*)d_ws;
    u16* hlnb = (u16*)ws;
    size_t off = (size_t)NB_ * 128 * 2;  // 64 MB bf16 hln row-major
    float* Wh    = (float*)(ws + off); off += 66 * 128 * 4;
    float* bh    = (float*)(ws + off); off += 128 * 4;
    float* slots = (float*)(ws + off); off += 64 * 128 * 4;
    float* qt    = (float*)(ws + off); off += 64 * 128 * 4;
    float* qc    = (float*)(ws + off); off += 64 * 4;
    float* vecp  = (float*)(ws + off); off += (size_t)1024 * 1024 * 4;  // 4 MB
    float* denp  = (float*)(ws + off); off += 1024 * 8 * 4;
    float* wihT  = (float*)(ws + off); off += 384 * 128 * 4;
    float* whhT  = (float*)(ws + off); off += 384 * 128 * 4;
    float* wkT   = (float*)(ws + off); off += 128 * 128 * 4;
    u16* whiT    = (u16*)(ws + off); off += 128 * 96 * 2;

    k0_transpose<<<448, 256, 0, stream>>>(gwih, gwhh, wk, wihT, whhT, wkT);
    k1_setup<<<1, 256, 0, stream>>>(w0, b0, w1, b1, w2, b2, w3, b3, w4, b4, w5, b5,
                                    w7, b7, mu, sg, Wh, bh, slots, whiT);
    k2_hln<<<NB_ / 128, 256, 0, stream>>>(inputs, embed, whiT, bh,
                                          ln_in_g, ln_in_b, hlnb);
    k3_q<<<64, 128, 0, stream>>>(slots, ln_sl_g, ln_sl_b, wq, bq, wkT, bk, qt, qc);
    for (int it = 0; it < 3; it++) {
        k4_attn<<<1024, 256, 0, stream>>>((const uint4*)hlnb, qt, qc, vecp, denp);
        k5_update<<<64, 512, 0, stream>>>(vecp, denp, wv, bv, wihT, whhT, gbih, gbhh,
                                          ln_ff_g, ln_ff_b, m1w, m1b, m2w, m2b, slots,
                                          ln_sl_g, ln_sl_b, wq, bq, wkT, bk, qt, qc,
                                          (float*)d_out, (it < 2) ? 1 : 0, (it == 2) ? 1 : 0);
    }
}